// Round 9
// baseline (361.903 us; speedup 1.0000x reference)
//
#include <hip/hip_runtime.h>
#include <hip/hip_bf16.h>

#define Hn 512
#define Wn 512
#define HWn (512 * 512)
#define KTOP 26214

#define HBS 70
#define HBROW (18 * HBS)   // 1260 u16 per point-row

typedef __attribute__((ext_vector_type(8))) short frag_ab;  // 8 bf16
typedef __attribute__((ext_vector_type(4))) float frag_cd;  // 4 fp32

__device__ __forceinline__ float sigf(float z) { return 1.0f / (1.0f + __expf(-z)); }

__device__ __forceinline__ short f2bf(float f) {  // RNE fp32 -> bf16
  unsigned u = __float_as_uint(f);
  u += 0x7FFFu + ((u >> 16) & 1u);
  return (short)(u >> 16);
}

__device__ __forceinline__ unsigned aload(const unsigned* p) {
  return __hip_atomic_load(p, __ATOMIC_RELAXED, __HIP_MEMORY_SCOPE_AGENT);
}

// ---- kernel 1: per (b,c) sums of x (color) + last-block runs weight-frag prep ----
__global__ __launch_bounds__(256) void k_means(
    const float* __restrict__ x, float* __restrict__ means, unsigned* __restrict__ doneCnt,
    const float* __restrict__ w1, const float* __restrict__ b1, const float* __restrict__ w2,
    const float* __restrict__ cw, const float* __restrict__ cb,
    short* __restrict__ w1A, short* __restrict__ w2A, int* __restrict__ kbTab,
    float* __restrict__ colorG)
{
  const int tid = threadIdx.x;
  __shared__ int lastS;
  int bc = blockIdx.x >> 5;
  int slice = blockIdx.x & 31;
  const float4* p = (const float4*)(x + bc * HWn + slice * 8192);
  float s = 0.f;
  for (int i = tid; i < 2048; i += 256) { float4 v = p[i]; s += v.x + v.y + v.z + v.w; }
  for (int off = 32; off > 0; off >>= 1) s += __shfl_down(s, off);
  if ((tid & 63) == 0) atomicAdd(&means[bc], s);
  __syncthreads();
  if (tid == 0) {
    unsigned tk = __hip_atomic_fetch_add(doneCnt, 1u, __ATOMIC_RELAXED, __HIP_MEMORY_SCOPE_AGENT);
    lastS = (tk == 767);
  }
  __syncthreads();
  if (!lastS) return;

  // ---- prep (runs once, after all means complete) ----
  {
    int chunk = tid >> 6, lane = tid & 63;
    int m = lane & 15, q = lane >> 4;
    for (int j = 0; j < 8; ++j) {
      int k = q * 8 + j;
      float v = (k < 27) ? w1[(chunk * 16 + m) * 27 + k] : 0.f;
      w1A[tid * 8 + j] = f2bf(v);
    }
  }
  if (tid < 64) {
    int q = tid >> 4;
    for (int j = 0; j < 8; ++j) {
      int k = q * 8 + j;
      int kk = (k < 27) ? k : (k - 27);
      int ic = kk / 9; int r = kk - ic * 9;
      kbTab[tid * 8 + j] = (ic * 240 + (r / 3) * 20 + (r % 3)) * 2;
    }
  }
  for (int i = tid; i < 384; i += 256) {
    int step = i >> 6, lane = i & 63;
    int m = lane & 15, q = lane >> 4;
    int dx = step >> 1, half = step & 1;
    int dy = m / 3, oc = m - dy * 3;
    for (int j = 0; j < 8; ++j) {
      int ch = half * 32 + q * 8 + j;
      float v = (m < 9) ? w2[oc * 576 + ch * 9 + dy * 3 + dx] : 0.f;
      w2A[i * 8 + j] = f2bf(v);
    }
  }
  if (tid < 24) {
    int b = tid / 3, oc = tid % 3;
    float z = cb[oc];
    for (int j = 0; j < 3; ++j)
      z += (atomicAdd(&means[b * 3 + j], 0.f) * (1.0f / (float)HWn)) * cw[oc * 3 + j];
    colorG[tid] = sigf(z);
  }
}

// ---- kernel 2: fused conv1+relu+conv2+sigmoid+color+1x1conv+x_out via MFMA ----
// Grid 32x64, z-loop over 8 batches (setup paid 2,048x not 16,384x).
// launch_bounds(256,6): R8's (256,4) capped occupancy at 36% and cost 3 us;
// this kernel's ~68 VGPR fits 6 waves/EU (<=80). T14 async-STAGE split:
// batch b+1's x loads are ISSUED right after conv1 of batch b (they touch
// only global memory) and land in registers; the ds_write happens at the
// next iteration top -> ~900-cycle HBM latency hides under conv2+epilogue.
// Named scalars only (rule #20: no runtime-indexed reg arrays).
__global__ __launch_bounds__(256, 6) void k_fused(
    const float* __restrict__ x, const float* __restrict__ b1,
    const float* __restrict__ b2, const float* __restrict__ convw, const float* __restrict__ convb,
    const short* __restrict__ w1Ag, const short* __restrict__ w2Ag,
    const int* __restrict__ kbTab,
    const float* __restrict__ colorG, float* __restrict__ out, float* __restrict__ Mb)
{
  __shared__ __align__(16) unsigned short xs[720];        // [3][12][20] bf16, halo-2
  __shared__ __align__(16) unsigned short hb[180 * HBS];  // h bf16: [pt][ch] stride 70
  __shared__ float bs[64];
  __shared__ float b2s[3], colorAll[24], cwS[12], cbS[4];

  const int tid = threadIdx.x;
  const int wid = tid >> 6, lane = tid & 63;
  const int n = lane & 15, q = lane >> 4;
  const int tx0 = blockIdx.x * 16, ty0 = blockIdx.y * 8;
  const bool inter = (blockIdx.x - 1u) < 30u && (blockIdx.y - 1u) < 62u;

  if (tid < 64) bs[tid] = b1[tid];
  if (tid < 3)  b2s[tid] = b2[tid];
  if (tid < 24) colorAll[tid] = colorG[tid];
  if (tid < 12) cwS[tid] = convw[tid];
  if (tid < 4)  cbS[tid] = convb[tid];

  // staging geometry (z-invariant): thread -> (c, yy, xq) of the 3x12x20 tile
  bool sOn = tid < 180;
  int rowBase = 0, chanOff = 0;
  unsigned short* sDst = xs;
  bool ok0 = false, ok1 = false, ok2 = false, ok3 = false;
  if (sOn) {
    int c = tid / 60, rem = tid - c * 60;
    int yy = rem / 5, xq = (rem - yy * 5) * 4;
    int gy = ty0 - 2 + yy, gx0 = tx0 - 2 + xq;
    rowBase = (gy << 9) + gx0;
    chanOff = c * HWn;
    sDst = xs + c * 240 + yy * 20 + xq;
    bool rowok = (unsigned)gy < 512u;
    ok0 = inter || (rowok && (unsigned)(gx0 + 0) < 512u);
    ok1 = inter || (rowok && (unsigned)(gx0 + 1) < 512u);
    ok2 = inter || (rowok && (unsigned)(gx0 + 2) < 512u);
    ok3 = inter || (rowok && (unsigned)(gx0 + 3) < 512u);
  }

  frag_ab w1f[4];
#pragma unroll
  for (int ck = 0; ck < 4; ++ck) w1f[ck] = *(const frag_ab*)(w1Ag + (ck * 64 + lane) * 8);
  frag_ab w2f[6];
#pragma unroll
  for (int i = 0; i < 6; ++i) w2f[i] = *(const frag_ab*)(w2Ag + (i * 64 + lane) * 8);

  // conv1 tap byte-offsets from global table (L2-hot, 2x dwordx4)
  int kb[8];
  {
    const int4* kp = (const int4*)(kbTab + lane * 8);
    int4 ka = kp[0], kc = kp[1];
    kb[0] = ka.x; kb[1] = ka.y; kb[2] = ka.z; kb[3] = ka.w;
    kb[4] = kc.x; kb[5] = kc.y; kb[6] = kc.z; kb[7] = kc.w;
  }

  // conv1 group geometry (z-invariant): groups {wid, wid+4, wid+8}
  int baseA[3], stA[3];
  bool keepA[3];
#pragma unroll
  for (int u = 0; u < 3; ++u) {
    int pt = (wid + u * 4) * 16 + n;
    int ptc = (pt < 180) ? pt : 179;   // pad lanes clamp read AND store (benign same-value race)
    int pty = (ptc * 3641) >> 16;      // /18 exact
    int ptx = ptc - pty * 18;
    baseA[u] = (pty * 20 + ptx) * 2;
    stA[u] = ptc * HBS + q * 4;
    int gy = ty0 - 1 + pty, gx = tx0 - 1 + ptx;
    keepA[u] = inter || ((unsigned)gy < 512u && (unsigned)gx < 512u);
  }
  __syncthreads();

  // bias for conv1 C-init: D row = q*4 + reg
  float biasr[4][4];
#pragma unroll
  for (int ck = 0; ck < 4; ++ck)
#pragma unroll
    for (int r = 0; r < 4; ++r) biasr[ck][r] = bs[ck * 16 + q * 4 + r];

  // prologue: issue batch-0 x loads (land during the const staging above)
  float v0 = 0.f, v1 = 0.f, v2 = 0.f, v3 = 0.f;
  if (sOn) {
    const float* rp = x + chanOff + rowBase;
    if (ok0) v0 = rp[0];
    if (ok1) v1 = rp[1];
    if (ok2) v2 = rp[2];
    if (ok3) v3 = rp[3];
  }

#pragma unroll 1
  for (int b = 0; b < 8; ++b) {
    // ---- write staged x (already in regs) to LDS as bf16 ----
    if (sOn) {
      __hip_bfloat162 c01 = __float22bfloat162_rn(make_float2(v0, v1));
      __hip_bfloat162 c23 = __float22bfloat162_rn(make_float2(v2, v3));
      uint2 v2w; v2w.x = *(unsigned*)&c01; v2w.y = *(unsigned*)&c23;
      *(uint2*)sDst = v2w;
    }
    __syncthreads();

    // ---- conv1: 180 points (12 groups of 16), 4 ch-chunks ----
#pragma unroll
    for (int u = 0; u < 3; ++u) {
      frag_ab B;
#pragma unroll
      for (int j = 0; j < 8; ++j)
        B[j] = *(const short*)((const char*)xs + baseA[u] + kb[j]);
#pragma unroll
      for (int ck = 0; ck < 4; ++ck) {
        frag_cd D = {biasr[ck][0], biasr[ck][1], biasr[ck][2], biasr[ck][3]};
        D = __builtin_amdgcn_mfma_f32_16x16x32_bf16(w1f[ck], B, D, 0, 0, 0);
        float2 p01 = make_float2(fmaxf(D[0], 0.f), fmaxf(D[1], 0.f));
        float2 p23 = make_float2(fmaxf(D[2], 0.f), fmaxf(D[3], 0.f));
        __hip_bfloat162 c01 = __float22bfloat162_rn(p01);  // v_cvt_pk_bf16_f32
        __hip_bfloat162 c23 = __float22bfloat162_rn(p23);
        unsigned lo = keepA[u] ? *(unsigned*)&c01 : 0u;
        unsigned hi = keepA[u] ? *(unsigned*)&c23 : 0u;
        uint2 v2; v2.x = lo; v2.y = hi;
        *(uint2*)(hb + stA[u] + ck * 16) = v2;
      }
    }

    // ---- T14: issue next batch's x loads NOW (global-only; latency hides
    // under conv2 + epilogue; consumed at next iteration's LDS write) ----
    float n0 = 0.f, n1 = 0.f, n2 = 0.f, n3 = 0.f;
    if (b < 7 && sOn) {
      const float* rp = x + (b + 1) * 3 * HWn + chanOff + rowBase;
      if (ok0) n0 = rp[0];
      if (ok1) n1 = rp[1];
      if (ok2) n2 = rp[2];
      if (ok3) n3 = rp[3];
    }
    __syncthreads();

    // ---- conv2: per point-row r (10 rows), 6 K-steps; D -> dstore overlaid
    // on hb row r (only this wave reads row r; reads precede writes) ----
    for (int r = wid; r < 10; r += 4) {
      frag_cd acc = {0.f, 0.f, 0.f, 0.f};
#pragma unroll
      for (int i = 0; i < 6; ++i) {
        int dx = i >> 1;
        int chb = (i & 1) * 64 + q * 16;  // byte offset within point's 140B ch-row
        frag_ab Bf = *(const frag_ab*)((const char*)hb + (r * 18 + n + dx) * (HBS * 2) + chb);
        acc = __builtin_amdgcn_mfma_f32_16x16x32_bf16(w2f[i], Bf, acc, 0, 0, 0);
      }
      float* dp = (float*)(hb + r * HBROW) + n * 10 + q * 4;
      if (q < 2) {
        *(float2*)dp = make_float2(acc[0], acc[1]);
        *(float2*)(dp + 2) = make_float2(acc[2], acc[3]);
      } else if (q == 2) {
        dp[0] = acc[0];
      }
    }
    __syncthreads();

    // ---- epilogue: 128 threads, one pixel each; also writes channel-max M ----
    if (tid < 128) {
      int y = tid >> 4, xcol = tid & 15;
      float a0 = b2s[0], a1 = b2s[1], a2 = b2s[2];
#pragma unroll
      for (int dy = 0; dy < 3; ++dy) {
        const float* dp = (const float*)(hb + (y + dy) * HBROW) + xcol * 10 + dy * 3;
        a0 += dp[0]; a1 += dp[1]; a2 += dp[2];
      }
      float ih0 = colorAll[b * 3 + 0] * sigf(a0);
      float ih1 = colorAll[b * 3 + 1] * sigf(a1);
      float ih2 = colorAll[b * 3 + 2] * sigf(a2);
      float Kv = cwS[0] * ih0 + cwS[1]  * ih1 + cwS[2]  * ih2 + cbS[0];
      float f1 = cwS[3] * ih0 + cwS[4]  * ih1 + cwS[5]  * ih2 + cbS[1];
      float f2 = cwS[6] * ih0 + cwS[7]  * ih1 + cwS[8]  * ih2 + cbS[2];
      float f3 = cwS[9] * ih0 + cwS[10] * ih1 + cwS[11] * ih2 + cbS[3];
      float xc0 = __bfloat162float(*(const __hip_bfloat16*)&xs[0 * 240 + (y + 2) * 20 + (xcol + 2)]);
      float xc1 = __bfloat162float(*(const __hip_bfloat16*)&xs[1 * 240 + (y + 2) * 20 + (xcol + 2)]);
      float xc2 = __bfloat162float(*(const __hip_bfloat16*)&xs[2 * 240 + (y + 2) * 20 + (xcol + 2)]);
      int oi = ((ty0 + y) << 9) + (tx0 + xcol);
      float o0 = Kv * xc0 - f1 + xc0;
      float o1 = Kv * xc1 - f2 + xc1;
      float o2 = Kv * xc2 - f3 + xc2;
      out[(b * 3 + 0) * HWn + oi] = o0;
      out[(b * 3 + 1) * HWn + oi] = o1;
      out[(b * 3 + 2) * HWn + oi] = o2;
      Mb[b * HWn + oi] = fmaxf(fmaxf(o0, o1), o2);  // v_max3_f32
    }
    __syncthreads();  // xs/hb reads done before next iteration's staging

    v0 = n0; v1 = n1; v2 = n2; v3 = n3;
  }
}

// ---- per-batch soft barrier, NO cache-wide fences ----
__device__ __forceinline__ void softBarrier(unsigned* ctr, unsigned target) {
  __syncthreads();
  if (threadIdx.x == 0) {
    __hip_atomic_fetch_add(ctr, 1u, __ATOMIC_RELAXED, __HIP_MEMORY_SCOPE_AGENT);
    while (__hip_atomic_load(ctr, __ATOMIC_RELAXED, __HIP_MEMORY_SCOPE_AGENT) < target)
      __builtin_amdgcn_s_sleep(2);
  }
  __syncthreads();
}

// ---- selection helpers reading completed global hists via agent-scope loads ----
__device__ void sel256(const unsigned* __restrict__ h, unsigned kneed,
                       unsigned* sm, unsigned* oBin, unsigned* oAbove)
{
  const int t = threadIdx.x;
  sm[t] = aload(&h[t]);
  __syncthreads();
  for (int d = 1; d < 256; d <<= 1) {
    unsigned add = (t + d < 256) ? sm[t + d] : 0u;
    __syncthreads();
    sm[t] += add;
    __syncthreads();
  }
  unsigned mine = sm[t];
  unsigned nxt = (t < 255) ? sm[t + 1] : 0u;
  if (mine >= kneed && nxt < kneed) { *oBin = (unsigned)t; *oAbove = nxt; }
  __syncthreads();
}

__device__ void sel4096(const unsigned* __restrict__ h, unsigned kneed,
                        unsigned* sm, unsigned* oBin, unsigned* oAbove)
{
  const int t = threadIdx.x;
  unsigned loc[16]; unsigned sum = 0;
#pragma unroll
  for (int i = 0; i < 16; ++i) { loc[i] = aload(&h[t * 16 + i]); sum += loc[i]; }
  sm[t] = sum;
  __syncthreads();
  for (int d = 1; d < 256; d <<= 1) {
    unsigned add = (t + d < 256) ? sm[t + d] : 0u;
    __syncthreads();
    sm[t] += add;
    __syncthreads();
  }
  unsigned mine = sm[t];
  unsigned nxt = (t < 255) ? sm[t + 1] : 0u;
  if (mine >= kneed && nxt < kneed) {
    unsigned acc = nxt;
    for (int i = 15; i >= 0; --i) {
      unsigned c = loc[i];
      if (acc + c >= kneed) { *oBin = (unsigned)(t * 16 + i); *oAbove = acc; break; }
      acc += c;
    }
  }
  __syncthreads();
}

// ---- kernel 3 (persistent, 2 soft barriers): M -> bright(LDS) -> h1 -> h12 -> accum ----
__global__ __launch_bounds__(256) void k_tail(
    const float* __restrict__ Mbuf, const float* __restrict__ outv,
    unsigned* __restrict__ h1, unsigned* __restrict__ h12,
    unsigned* __restrict__ eqTaken, float* __restrict__ Asum,
    unsigned* __restrict__ barCtr, unsigned* __restrict__ doneCnt, float* __restrict__ outA)
{
  // union region: phase 1a uses xm[10][516] f32 (20640 B); phases 1b..3 use
  // hh[4096] u32 (16384 B) + sm[256] u32 (1024 B). Disjoint live ranges.
  __shared__ __align__(16) char smem[20640];
  __shared__ __align__(16) float brightS[4096];  // 8 rows x 512
  __shared__ unsigned sB1, sA1, sB2, sA2;
  __shared__ float red[4][3];
  __shared__ int lastA;

  float (*xm)[516] = (float (*)[516])smem;
  unsigned* hh = (unsigned*)smem;
  unsigned* sm = (unsigned*)(smem + 16384);

  const int tid = threadIdx.x;
  const int b = blockIdx.x >> 6, strip = blockIdx.x & 63;
  const int y0 = strip * 8;
  const float* mp = Mbuf + b * HWn;
  const float* op = outv + b * 3 * HWn;
  unsigned* bar = barCtr + b * 48;  // 2 barriers x 64B stride

  // ---- phase 1a: stage M (reflect halo) -> xm, compute bright -> brightS ----
  for (int idx = tid; idx < 1280; idx += 256) {
    int r = idx >> 7, seg = idx & 127;
    int gy = y0 - 1 + r; gy = (gy < 0) ? -gy : (gy > 511 ? 1022 - gy : gy);
    int c0 = seg * 4;
    float4 v = *(const float4*)(mp + (gy << 9) + c0);
    xm[r][c0 + 1] = v.x;
    xm[r][c0 + 2] = v.y;
    xm[r][c0 + 3] = v.z;
    xm[r][c0 + 4] = v.w;
  }
  if (tid < 20) {
    int r = tid >> 1, side = tid & 1;
    int gy = y0 - 1 + r; gy = (gy < 0) ? -gy : (gy > 511 ? 1022 - gy : gy);
    int gx = side ? 510 : 1;  // reflect of col 512 / col -1
    xm[r][side ? 513 : 0] = mp[(gy << 9) + gx];
  }
  __syncthreads();
  {
    const int row = tid >> 5, cl = tid & 31;
#pragma unroll 4
    for (int i = 0; i < 16; ++i) {
      int c = cl + (i << 5);   // consecutive lanes -> consecutive cols
      float s0 = xm[row][c]     + xm[row][c + 1]     + xm[row][c + 2];
      float s1 = xm[row + 1][c] + xm[row + 1][c + 1] + xm[row + 1][c + 2];
      float s2 = xm[row + 2][c] + xm[row + 2][c + 1] + xm[row + 2][c + 2];
      float s = (s0 + s1 + s2) * (1.f / 9.f) + xm[row + 1][c + 1] * (8.f / 9.f);
      s = fmaxf(s, 0.f);
      brightS[(row << 9) + c] = s;
    }
  }
  __syncthreads();  // xm dead from here; hh/sm own the union region

  // ---- phase 1b: 256-bin h1 from brightS (register-cached exponent bins) ----
  hh[tid] = 0;
  __syncthreads();
  {
    unsigned cb0 = 0x100, cc0 = 0, cb1 = 0x100, cc1 = 0;
    const float4* bp4 = (const float4*)brightS;
#pragma unroll
    for (int it = 0; it < 4; ++it) {
      float4 v = bp4[it * 256 + tid];
      unsigned bins[4] = { __float_as_uint(v.x) >> 24, __float_as_uint(v.y) >> 24,
                           __float_as_uint(v.z) >> 24, __float_as_uint(v.w) >> 24 };
#pragma unroll
      for (int j = 0; j < 4; ++j) {
        unsigned bb = bins[j];
        if (bb == cb0) ++cc0;
        else if (bb == cb1) ++cc1;
        else if (!cc0) { cb0 = bb; cc0 = 1; }
        else if (!cc1) { cb1 = bb; cc1 = 1; }
        else atomicAdd(&hh[bb], 1u);
      }
    }
    if (cc0) atomicAdd(&hh[cb0], cc0);
    if (cc1) atomicAdd(&hh[cb1], cc1);
  }
  __syncthreads();
  if (hh[tid]) atomicAdd(&h1[(b << 8) + tid], hh[tid]);
  softBarrier(bar, 64);

  // ---- phase 2: level-1 select + 4096-bin level-2 hist over own pixels ----
  sel256(h1 + (b << 8), KTOP, sm, &sB1, &sA1);
  for (int i = tid; i < 4096; i += 256) hh[i] = 0;
  __syncthreads();
  const float4* bp = (const float4*)brightS;
  const unsigned sb1 = sB1;
#pragma unroll
  for (int it = 0; it < 4; ++it) {
    float4 v = bp[it * 256 + tid];
    unsigned u0 = __float_as_uint(v.x), u1 = __float_as_uint(v.y);
    unsigned u2 = __float_as_uint(v.z), u3 = __float_as_uint(v.w);
    if ((u0 >> 24) == sb1) atomicAdd(&hh[(u0 >> 12) & 0xFFFu], 1u);
    if ((u1 >> 24) == sb1) atomicAdd(&hh[(u1 >> 12) & 0xFFFu], 1u);
    if ((u2 >> 24) == sb1) atomicAdd(&hh[(u2 >> 12) & 0xFFFu], 1u);
    if ((u3 >> 24) == sb1) atomicAdd(&hh[(u3 >> 12) & 0xFFFu], 1u);
  }
  __syncthreads();
  for (int i = tid; i < 4096; i += 256)
    if (hh[i]) atomicAdd(&h12[(b << 12) + i], hh[i]);
  if (tid == 0) { sB2 = 0xFFFu; sA2 = 0u; }  // null-select fallback
  softBarrier(bar + 16, 64);

  // ---- phase 3: level-2 select + accumulate picked values (20-bit prefix) ----
  sel4096(h12 + (b << 12), KTOP - sA1, sm, &sB2, &sA2);
  const unsigned T20 = (sB1 << 12) | sB2;
  const unsigned ne = KTOP - sA1 - sA2;
  float v0 = 0.f, v1 = 0.f, v2 = 0.f;
  for (int it = 0; it < 16; ++it) {
    int li = it * 256 + tid;
    int pix = (y0 << 9) + li;
    unsigned u20 = __float_as_uint(brightS[li]) >> 12;
    bool take = u20 > T20;
    if (u20 == T20) {
      if (aload(&eqTaken[b * 16]) < ne) {
        unsigned old = atomicAdd(&eqTaken[b * 16], 1u);
        take = old < ne;
      }
    }
    if (take) {  // reshape (C,H,W)->(H*W,C): pixel i -> flat 3i,3i+1,3i+2
      v0 += op[3 * pix];
      v1 += op[3 * pix + 1];
      v2 += op[3 * pix + 2];
    }
  }
  for (int off = 32; off > 0; off >>= 1) {
    v0 += __shfl_down(v0, off);
    v1 += __shfl_down(v1, off);
    v2 += __shfl_down(v2, off);
  }
  int w = tid >> 6;
  if ((tid & 63) == 0) { red[w][0] = v0; red[w][1] = v1; red[w][2] = v2; }
  __syncthreads();
  if (tid == 0) {
    atomicAdd(&Asum[b * 3 + 0], red[0][0] + red[1][0] + red[2][0] + red[3][0]);
    atomicAdd(&Asum[b * 3 + 1], red[0][1] + red[1][1] + red[2][1] + red[3][1]);
    atomicAdd(&Asum[b * 3 + 2], red[0][2] + red[1][2] + red[2][2] + red[3][2]);
  }
  __syncthreads();
  if (tid == 0) {
    unsigned tk = __hip_atomic_fetch_add(doneCnt, 1u, __ATOMIC_RELAXED, __HIP_MEMORY_SCOPE_AGENT);
    lastA = (tk == 511);
  }
  __syncthreads();
  if (lastA && tid < 24)
    outA[3 * HWn * 8 + tid] = atomicAdd(&Asum[tid], 0.f) * (1.0f / (float)KTOP);
}

extern "C" void kernel_launch(void* const* d_in, const int* in_sizes, int n_in,
                              void* d_out, int out_size, void* d_ws, size_t ws_size,
                              hipStream_t stream)
{
  const float* x     = (const float*)d_in[0];
  const float* w1    = (const float*)d_in[1];
  const float* b1    = (const float*)d_in[2];
  const float* w2    = (const float*)d_in[3];
  const float* b2    = (const float*)d_in[4];
  const float* cw    = (const float*)d_in[5];
  const float* cb    = (const float*)d_in[6];
  const float* convw = (const float*)d_in[7];
  const float* convb = (const float*)d_in[8];
  float* out = (float*)d_out;
  char* ws = (char*)d_ws;

  float*    Mbuf      = (float*)(ws);                // 8 MB (channel-max of out)
  unsigned* h1        = (unsigned*)(ws + 8388608);   // 8192
  unsigned* h12       = (unsigned*)(ws + 8396800);   // 131072
  float*    Asum      = (float*)(ws + 8658944);      // 96
  unsigned* eqTaken   = (unsigned*)(ws + 8659040);   // 8*16 u32 = 512 B (padded)
  float*    means     = (float*)(ws + 8659552);      // 96
  unsigned* meansDone = (unsigned*)(ws + 8659648);   // 32
  unsigned* accumDone = (unsigned*)(ws + 8659680);   // 32
  unsigned* barCtr    = (unsigned*)(ws + 8659712);   // 8 batches x 3 x 64B = 1536
  short*    w1Ag      = (short*)(ws + 8661248);      // 4096 B (16-aligned)
  short*    w2Ag      = (short*)(ws + 8665344);      // 6144 B used
  float*    colorG    = (float*)(ws + 8683776);      // 96
  int*      kbTab     = (int*)(ws + 8683904);        // 64 lanes x 8 ints = 2048 B

  // zero h1..barCtr
  hipMemsetAsync(ws + 8388608, 0, 8661248 - 8388608, stream);

  k_means<<<768, 256, 0, stream>>>(x, means, meansDone, w1, b1, w2, cw, cb, w1Ag, w2Ag, kbTab, colorG);
  k_fused<<<dim3(32, 64), 256, 0, stream>>>(x, b1, b2, convw, convb, w1Ag, w2Ag, kbTab, colorG, out, Mbuf);
  k_tail<<<512, 256, 0, stream>>>(Mbuf, out, h1, h12, eqTaken, Asum, barCtr, accumDone, out);
}

// Round 10
// 244.440 us; speedup vs baseline: 1.4805x; 1.4805x over previous
//
#include <hip/hip_runtime.h>
#include <hip/hip_bf16.h>

#define Hn 512
#define Wn 512
#define HWn (512 * 512)
#define KTOP 26214

// hb point stride: 70 u16 = 140 B = 35 dwords (odd) -> conv2 ds_read_b128
// lane bank-start (3n+4q) mod 32, <=2-way aliasing. LDS 26,984 B ->
// 6 blocks/CU cap. (R7-verified best: 83.6 us, no spill.)
#define HBS 70
#define HBROW (18 * HBS)   // 1260 u16 per point-row

typedef __attribute__((ext_vector_type(8))) short frag_ab;  // 8 bf16
typedef __attribute__((ext_vector_type(4))) float frag_cd;  // 4 fp32

__device__ __forceinline__ float sigf(float z) { return 1.0f / (1.0f + __expf(-z)); }

__device__ __forceinline__ short f2bf(float f) {  // RNE fp32 -> bf16
  unsigned u = __float_as_uint(f);
  u += 0x7FFFu + ((u >> 16) & 1u);
  return (short)(u >> 16);
}

__device__ __forceinline__ unsigned aload(const unsigned* p) {
  return __hip_atomic_load(p, __ATOMIC_RELAXED, __HIP_MEMORY_SCOPE_AGENT);
}

// ---- kernel 1: per (b,c) sums of x (color) + last-block runs weight-frag prep ----
__global__ __launch_bounds__(256) void k_means(
    const float* __restrict__ x, float* __restrict__ means, unsigned* __restrict__ doneCnt,
    const float* __restrict__ w1, const float* __restrict__ b1, const float* __restrict__ w2,
    const float* __restrict__ cw, const float* __restrict__ cb,
    short* __restrict__ w1A, short* __restrict__ w2A, int* __restrict__ kbTab,
    float* __restrict__ colorG)
{
  const int tid = threadIdx.x;
  __shared__ int lastS;
  int bc = blockIdx.x >> 5;
  int slice = blockIdx.x & 31;
  const float4* p = (const float4*)(x + bc * HWn + slice * 8192);
  float s = 0.f;
  for (int i = tid; i < 2048; i += 256) { float4 v = p[i]; s += v.x + v.y + v.z + v.w; }
  for (int off = 32; off > 0; off >>= 1) s += __shfl_down(s, off);
  if ((tid & 63) == 0) atomicAdd(&means[bc], s);
  __syncthreads();
  if (tid == 0) {
    unsigned tk = __hip_atomic_fetch_add(doneCnt, 1u, __ATOMIC_RELAXED, __HIP_MEMORY_SCOPE_AGENT);
    lastS = (tk == 767);
  }
  __syncthreads();
  if (!lastS) return;

  // ---- prep (runs once, after all means complete) ----
  // conv1 A-frags: M=64 out-ch (4 chunks of 16), K = 27 taps; slots 27..31
  // are ZERO weights (bias enters via MFMA C-operand in k_fused).
  {
    int chunk = tid >> 6, lane = tid & 63;
    int m = lane & 15, q = lane >> 4;
    for (int j = 0; j < 8; ++j) {
      int k = q * 8 + j;
      float v = (k < 27) ? w1[(chunk * 16 + m) * 27 + k] : 0.f;
      w1A[tid * 8 + j] = f2bf(v);
    }
  }
  // conv1 im2col tap byte-offsets per (lane, j) — replaces per-thread div/mod
  // chains in k_fused with two dwordx4 loads. Slots >=27 dup taps 0..4.
  if (tid < 64) {
    int q = tid >> 4;
    for (int j = 0; j < 8; ++j) {
      int k = q * 8 + j;
      int kk = (k < 27) ? k : (k - 27);
      int ic = kk / 9; int r = kk - ic * 9;
      kbTab[tid * 8 + j] = (ic * 240 + (r / 3) * 20 + (r % 3)) * 2;
    }
  }
  // conv2 A-frags, (dy,oc)-packed: M rows m = dy*3+oc (9 used of 16),
  // K-order = dx-major, ch-minor: step i -> dx=i>>1, ch-half=i&1. 6 steps.
  for (int i = tid; i < 384; i += 256) {
    int step = i >> 6, lane = i & 63;
    int m = lane & 15, q = lane >> 4;
    int dx = step >> 1, half = step & 1;
    int dy = m / 3, oc = m - dy * 3;
    for (int j = 0; j < 8; ++j) {
      int ch = half * 32 + q * 8 + j;
      float v = (m < 9) ? w2[oc * 576 + ch * 9 + dy * 3 + dx] : 0.f;
      w2A[i * 8 + j] = f2bf(v);
    }
  }
  if (tid < 24) {
    int b = tid / 3, oc = tid % 3;
    float z = cb[oc];
    for (int j = 0; j < 3; ++j)
      z += (atomicAdd(&means[b * 3 + j], 0.f) * (1.0f / (float)HWn)) * cw[oc * 3 + j];
    colorG[tid] = sigf(z);
  }
}

// ---- kernel 2: fused conv1+relu+conv2+sigmoid+color+1x1conv+x_out via MFMA ----
// Single 16x8 tile/block (R7-verified best). conv1: bias via C-init, dup-tap
// K-padding, kb from global table, NO ptok: pad lanes (pt 180..191) clamp
// BOTH read and store to point 179 (benign same-value race). Interior blocks
// (93%) skip bounds checks. dstore overlays hb. LDS 26,984 B.
// NOTE (R3/R9 lesson, confirmed twice): any scheme extending per-thread live
// ranges across a tile/batch loop (multi-tile amortization, register
// prefetch) spills to scratch here -> 400-700 MB HBM traffic. Do not revisit.
__global__ __launch_bounds__(256, 6) void k_fused(
    const float* __restrict__ x, const float* __restrict__ b1,
    const float* __restrict__ b2, const float* __restrict__ convw, const float* __restrict__ convb,
    const short* __restrict__ w1Ag, const short* __restrict__ w2Ag,
    const int* __restrict__ kbTab,
    const float* __restrict__ colorG, float* __restrict__ out, float* __restrict__ Mb)
{
  __shared__ __align__(16) unsigned short xs[720];        // [3][12][20] bf16, halo-2
  __shared__ __align__(16) unsigned short hb[180 * HBS];  // h bf16: [pt][ch] stride 70
  __shared__ float bs[64];
  __shared__ float b2s[3], colorS[3], cwS[12], cbS[4];

  const int tid = threadIdx.x;
  const int wid = tid >> 6, lane = tid & 63;
  const int n = lane & 15, q = lane >> 4;
  const int tx0 = blockIdx.x * 16, ty0 = blockIdx.y * 8;
  const int b = blockIdx.z;
  const bool inter = (blockIdx.x - 1u) < 30u && (blockIdx.y - 1u) < 62u;

  // stage x tile as bf16 (4 px/thread, cvt_pk + ds_write_b64):
  // rows ty0-2..ty0+9, cols tx0-2..tx0+17, zero outside image
  if (tid < 180) {
    int c = tid / 60, rem = tid - c * 60;
    int yy = rem / 5, xq = (rem - yy * 5) * 4;
    int gy = ty0 - 2 + yy, gx0 = tx0 - 2 + xq;
    const float* rp = x + (b * 3 + c) * HWn + (gy << 9) + gx0;
    float v0, v1, v2, v3;
    if (inter) {
      v0 = rp[0]; v1 = rp[1]; v2 = rp[2]; v3 = rp[3];
    } else {
      bool rowok = (unsigned)gy < 512u;
      v0 = (rowok && (unsigned)(gx0 + 0) < 512u) ? rp[0] : 0.f;
      v1 = (rowok && (unsigned)(gx0 + 1) < 512u) ? rp[1] : 0.f;
      v2 = (rowok && (unsigned)(gx0 + 2) < 512u) ? rp[2] : 0.f;
      v3 = (rowok && (unsigned)(gx0 + 3) < 512u) ? rp[3] : 0.f;
    }
    __hip_bfloat162 c01 = __float22bfloat162_rn(make_float2(v0, v1));
    __hip_bfloat162 c23 = __float22bfloat162_rn(make_float2(v2, v3));
    uint2 v2w; v2w.x = *(unsigned*)&c01; v2w.y = *(unsigned*)&c23;
    *(uint2*)(xs + c * 240 + yy * 20 + xq) = v2w;
  }
  if (tid < 64) bs[tid] = b1[tid];
  if (tid < 3)  b2s[tid] = b2[tid];
  if (tid < 3)  colorS[tid] = colorG[b * 3 + tid];
  if (tid < 12) cwS[tid] = convw[tid];
  if (tid < 4)  cbS[tid] = convb[tid];

  frag_ab w1f[4];
#pragma unroll
  for (int ck = 0; ck < 4; ++ck) w1f[ck] = *(const frag_ab*)(w1Ag + (ck * 64 + lane) * 8);

  // conv1 tap byte-offsets from global table (L2-hot, 2x dwordx4)
  int kb[8];
  {
    const int4* kp = (const int4*)(kbTab + lane * 8);
    int4 ka = kp[0], kc = kp[1];
    kb[0] = ka.x; kb[1] = ka.y; kb[2] = ka.z; kb[3] = ka.w;
    kb[4] = kc.x; kb[5] = kc.y; kb[6] = kc.z; kb[7] = kc.w;
  }
  __syncthreads();

  // bias for C-init: D row = q*4 + reg
  float biasr[4][4];
#pragma unroll
  for (int ck = 0; ck < 4; ++ck)
#pragma unroll
    for (int r = 0; r < 4; ++r) biasr[ck][r] = bs[ck * 16 + q * 4 + r];

  // ---- conv1: 180 points (12 groups of 16), 4 ch-chunks ----
  if (inter) {
    for (int g = wid; g < 12; g += 4) {
      int pt = g * 16 + n;
      int ptc = (pt < 180) ? pt : 179;   // pad lanes: clamped read AND store
      int pty = (ptc * 3641) >> 16;      // /18 exact
      int ptx = ptc - pty * 18;
      int baseB = (pty * 20 + ptx) * 2;
      frag_ab B;
#pragma unroll
      for (int j = 0; j < 8; ++j)
        B[j] = *(const short*)((const char*)xs + baseB + kb[j]);
#pragma unroll
      for (int ck = 0; ck < 4; ++ck) {
        frag_cd D = {biasr[ck][0], biasr[ck][1], biasr[ck][2], biasr[ck][3]};
        D = __builtin_amdgcn_mfma_f32_16x16x32_bf16(w1f[ck], B, D, 0, 0, 0);
        float2 p01 = make_float2(fmaxf(D[0], 0.f), fmaxf(D[1], 0.f));
        float2 p23 = make_float2(fmaxf(D[2], 0.f), fmaxf(D[3], 0.f));
        __hip_bfloat162 c01 = __float22bfloat162_rn(p01);  // v_cvt_pk_bf16_f32
        __hip_bfloat162 c23 = __float22bfloat162_rn(p23);
        uint2 v2; v2.x = *(unsigned*)&c01; v2.y = *(unsigned*)&c23;
        *(uint2*)(hb + ptc * HBS + ck * 16 + q * 4) = v2;  // pad lanes: same bytes, same addr
      }
    }
  } else {
    for (int g = wid; g < 12; g += 4) {
      int pt = g * 16 + n;
      int ptc = (pt < 180) ? pt : 179;
      int pty = (ptc * 3641) >> 16;
      int ptx = ptc - pty * 18;
      int baseB = (pty * 20 + ptx) * 2;
      int gy = ty0 - 1 + pty, gx = tx0 - 1 + ptx;
      bool valid = (unsigned)gy < 512u && (unsigned)gx < 512u;
      frag_ab B;
#pragma unroll
      for (int j = 0; j < 8; ++j)
        B[j] = *(const short*)((const char*)xs + baseB + kb[j]);
#pragma unroll
      for (int ck = 0; ck < 4; ++ck) {
        frag_cd D = {biasr[ck][0], biasr[ck][1], biasr[ck][2], biasr[ck][3]};
        D = __builtin_amdgcn_mfma_f32_16x16x32_bf16(w1f[ck], B, D, 0, 0, 0);
        float2 p01 = make_float2(fmaxf(D[0], 0.f), fmaxf(D[1], 0.f));
        float2 p23 = make_float2(fmaxf(D[2], 0.f), fmaxf(D[3], 0.f));
        __hip_bfloat162 c01 = __float22bfloat162_rn(p01);
        __hip_bfloat162 c23 = __float22bfloat162_rn(p23);
        unsigned lo = valid ? *(unsigned*)&c01 : 0u;
        unsigned hi = valid ? *(unsigned*)&c23 : 0u;
        uint2 v2; v2.x = lo; v2.y = hi;
        *(uint2*)(hb + ptc * HBS + ck * 16 + q * 4) = v2;
      }
    }
  }

  // conv2 A-frags (6 K-steps), issued before the barrier so loads overlap it
  frag_ab w2f[6];
#pragma unroll
  for (int i = 0; i < 6; ++i) w2f[i] = *(const frag_ab*)(w2Ag + (i * 64 + lane) * 8);
  __syncthreads();

  // ---- conv2: per point-row r (10 rows), 6 K-steps; D -> dstore overlaid on
  // hb row r (only this wave reads row r, reads complete before writes) ----
  for (int r = wid; r < 10; r += 4) {
    frag_cd acc = {0.f, 0.f, 0.f, 0.f};
#pragma unroll
    for (int i = 0; i < 6; ++i) {
      int dx = i >> 1;
      int chb = (i & 1) * 64 + q * 16;  // byte offset within point's 140B ch-row
      frag_ab Bf = *(const frag_ab*)((const char*)hb + (r * 18 + n + dx) * (HBS * 2) + chb);
      acc = __builtin_amdgcn_mfma_f32_16x16x32_bf16(w2f[i], Bf, acc, 0, 0, 0);
    }
    // D rows m = q*4+reg; only m<9 useful. lane (n,q) -> dstore[r][n*10 + m]
    float* dp = (float*)(hb + r * HBROW) + n * 10 + q * 4;
    if (q < 2) {
      *(float2*)dp = make_float2(acc[0], acc[1]);
      *(float2*)(dp + 2) = make_float2(acc[2], acc[3]);
    } else if (q == 2) {
      dp[0] = acc[0];
    }
  }
  __syncthreads();

  // ---- epilogue: 128 threads, one pixel each; also writes channel-max M ----
  if (tid < 128) {
    int y = tid >> 4, xcol = tid & 15;
    float a0 = b2s[0], a1 = b2s[1], a2 = b2s[2];
#pragma unroll
    for (int dy = 0; dy < 3; ++dy) {
      const float* dp = (const float*)(hb + (y + dy) * HBROW) + xcol * 10 + dy * 3;
      a0 += dp[0]; a1 += dp[1]; a2 += dp[2];
    }
    float ih0 = colorS[0] * sigf(a0);
    float ih1 = colorS[1] * sigf(a1);
    float ih2 = colorS[2] * sigf(a2);
    float Kv = cwS[0] * ih0 + cwS[1]  * ih1 + cwS[2]  * ih2 + cbS[0];
    float f1 = cwS[3] * ih0 + cwS[4]  * ih1 + cwS[5]  * ih2 + cbS[1];
    float f2 = cwS[6] * ih0 + cwS[7]  * ih1 + cwS[8]  * ih2 + cbS[2];
    float f3 = cwS[9] * ih0 + cwS[10] * ih1 + cwS[11] * ih2 + cbS[3];
    float xc0 = __bfloat162float(*(const __hip_bfloat16*)&xs[0 * 240 + (y + 2) * 20 + (xcol + 2)]);
    float xc1 = __bfloat162float(*(const __hip_bfloat16*)&xs[1 * 240 + (y + 2) * 20 + (xcol + 2)]);
    float xc2 = __bfloat162float(*(const __hip_bfloat16*)&xs[2 * 240 + (y + 2) * 20 + (xcol + 2)]);
    int oi = ((ty0 + y) << 9) + (tx0 + xcol);
    float o0 = Kv * xc0 - f1 + xc0;
    float o1 = Kv * xc1 - f2 + xc1;
    float o2 = Kv * xc2 - f3 + xc2;
    out[(b * 3 + 0) * HWn + oi] = o0;
    out[(b * 3 + 1) * HWn + oi] = o1;
    out[(b * 3 + 2) * HWn + oi] = o2;
    Mb[b * HWn + oi] = fmaxf(fmaxf(o0, o1), o2);  // v_max3_f32
  }
}

// ---- per-batch soft barrier, NO cache-wide fences ----
__device__ __forceinline__ void softBarrier(unsigned* ctr, unsigned target) {
  __syncthreads();
  if (threadIdx.x == 0) {
    __hip_atomic_fetch_add(ctr, 1u, __ATOMIC_RELAXED, __HIP_MEMORY_SCOPE_AGENT);
    while (__hip_atomic_load(ctr, __ATOMIC_RELAXED, __HIP_MEMORY_SCOPE_AGENT) < target)
      __builtin_amdgcn_s_sleep(2);
  }
  __syncthreads();
}

// ---- selection helpers reading completed global hists via agent-scope loads ----
__device__ void sel256(const unsigned* __restrict__ h, unsigned kneed,
                       unsigned* sm, unsigned* oBin, unsigned* oAbove)
{
  const int t = threadIdx.x;
  sm[t] = aload(&h[t]);
  __syncthreads();
  for (int d = 1; d < 256; d <<= 1) {
    unsigned add = (t + d < 256) ? sm[t + d] : 0u;
    __syncthreads();
    sm[t] += add;
    __syncthreads();
  }
  unsigned mine = sm[t];
  unsigned nxt = (t < 255) ? sm[t + 1] : 0u;
  if (mine >= kneed && nxt < kneed) { *oBin = (unsigned)t; *oAbove = nxt; }
  __syncthreads();
}

__device__ void sel4096(const unsigned* __restrict__ h, unsigned kneed,
                        unsigned* sm, unsigned* oBin, unsigned* oAbove)
{
  const int t = threadIdx.x;
  unsigned loc[16]; unsigned sum = 0;
#pragma unroll
  for (int i = 0; i < 16; ++i) { loc[i] = aload(&h[t * 16 + i]); sum += loc[i]; }
  sm[t] = sum;
  __syncthreads();
  for (int d = 1; d < 256; d <<= 1) {
    unsigned add = (t + d < 256) ? sm[t + d] : 0u;
    __syncthreads();
    sm[t] += add;
    __syncthreads();
  }
  unsigned mine = sm[t];
  unsigned nxt = (t < 255) ? sm[t + 1] : 0u;
  if (mine >= kneed && nxt < kneed) {
    unsigned acc = nxt;
    for (int i = 15; i >= 0; --i) {
      unsigned c = loc[i];
      if (acc + c >= kneed) { *oBin = (unsigned)(t * 16 + i); *oAbove = acc; break; }
      acc += c;
    }
  }
  __syncthreads();
}

// ---- kernel 3 (persistent, 2 soft barriers): M -> bright(LDS) -> h1 -> h12 -> accum ----
// 8-row strips, 512 blocks (64/batch). Phase 1 reads the 1-channel Mbuf.
// xm (phase-1a only) overlaid with hh/sm -> LDS ~37 KB.
// 20-bit threshold: ties share top 20 bits (spread <= 2^-11 relative);
// arbitrary pick of ne members perturbs the 26214-mean by < 4e-5.
__global__ __launch_bounds__(256) void k_tail(
    const float* __restrict__ Mbuf, const float* __restrict__ outv,
    unsigned* __restrict__ h1, unsigned* __restrict__ h12,
    unsigned* __restrict__ eqTaken, float* __restrict__ Asum,
    unsigned* __restrict__ barCtr, unsigned* __restrict__ doneCnt, float* __restrict__ outA)
{
  // union region: phase 1a uses xm[10][516] f32 (20640 B); phases 1b..3 use
  // hh[4096] u32 (16384 B) + sm[256] u32 (1024 B). Disjoint live ranges.
  __shared__ __align__(16) char smem[20640];
  __shared__ __align__(16) float brightS[4096];  // 8 rows x 512
  __shared__ unsigned sB1, sA1, sB2, sA2;
  __shared__ float red[4][3];
  __shared__ int lastA;

  float (*xm)[516] = (float (*)[516])smem;
  unsigned* hh = (unsigned*)smem;
  unsigned* sm = (unsigned*)(smem + 16384);

  const int tid = threadIdx.x;
  const int b = blockIdx.x >> 6, strip = blockIdx.x & 63;
  const int y0 = strip * 8;
  const float* mp = Mbuf + b * HWn;
  const float* op = outv + b * 3 * HWn;
  unsigned* bar = barCtr + b * 48;  // 2 barriers x 64B stride

  // ---- phase 1a: stage M (reflect halo) -> xm, compute bright -> brightS ----
  for (int idx = tid; idx < 1280; idx += 256) {
    int r = idx >> 7, seg = idx & 127;
    int gy = y0 - 1 + r; gy = (gy < 0) ? -gy : (gy > 511 ? 1022 - gy : gy);
    int c0 = seg * 4;
    float4 v = *(const float4*)(mp + (gy << 9) + c0);
    xm[r][c0 + 1] = v.x;
    xm[r][c0 + 2] = v.y;
    xm[r][c0 + 3] = v.z;
    xm[r][c0 + 4] = v.w;
  }
  if (tid < 20) {
    int r = tid >> 1, side = tid & 1;
    int gy = y0 - 1 + r; gy = (gy < 0) ? -gy : (gy > 511 ? 1022 - gy : gy);
    int gx = side ? 510 : 1;  // reflect of col 512 / col -1
    xm[r][side ? 513 : 0] = mp[(gy << 9) + gx];
  }
  __syncthreads();
  {
    const int row = tid >> 5, cl = tid & 31;
#pragma unroll 4
    for (int i = 0; i < 16; ++i) {
      int c = cl + (i << 5);   // consecutive lanes -> consecutive cols
      float s0 = xm[row][c]     + xm[row][c + 1]     + xm[row][c + 2];
      float s1 = xm[row + 1][c] + xm[row + 1][c + 1] + xm[row + 1][c + 2];
      float s2 = xm[row + 2][c] + xm[row + 2][c + 1] + xm[row + 2][c + 2];
      float s = (s0 + s1 + s2) * (1.f / 9.f) + xm[row + 1][c + 1] * (8.f / 9.f);
      s = fmaxf(s, 0.f);
      brightS[(row << 9) + c] = s;
    }
  }
  __syncthreads();  // xm dead from here; hh/sm own the union region

  // ---- phase 1b: 256-bin h1 from brightS (register-cached exponent bins) ----
  hh[tid] = 0;
  __syncthreads();
  {
    unsigned cb0 = 0x100, cc0 = 0, cb1 = 0x100, cc1 = 0;
    const float4* bp4 = (const float4*)brightS;
#pragma unroll
    for (int it = 0; it < 4; ++it) {
      float4 v = bp4[it * 256 + tid];
      unsigned bins[4] = { __float_as_uint(v.x) >> 24, __float_as_uint(v.y) >> 24,
                           __float_as_uint(v.z) >> 24, __float_as_uint(v.w) >> 24 };
#pragma unroll
      for (int j = 0; j < 4; ++j) {
        unsigned bb = bins[j];
        if (bb == cb0) ++cc0;
        else if (bb == cb1) ++cc1;
        else if (!cc0) { cb0 = bb; cc0 = 1; }
        else if (!cc1) { cb1 = bb; cc1 = 1; }
        else atomicAdd(&hh[bb], 1u);
      }
    }
    if (cc0) atomicAdd(&hh[cb0], cc0);
    if (cc1) atomicAdd(&hh[cb1], cc1);
  }
  __syncthreads();
  if (hh[tid]) atomicAdd(&h1[(b << 8) + tid], hh[tid]);
  softBarrier(bar, 64);

  // ---- phase 2: level-1 select + 4096-bin level-2 hist over own pixels ----
  sel256(h1 + (b << 8), KTOP, sm, &sB1, &sA1);
  for (int i = tid; i < 4096; i += 256) hh[i] = 0;
  __syncthreads();
  const float4* bp = (const float4*)brightS;
  const unsigned sb1 = sB1;
#pragma unroll
  for (int it = 0; it < 4; ++it) {
    float4 v = bp[it * 256 + tid];
    unsigned u0 = __float_as_uint(v.x), u1 = __float_as_uint(v.y);
    unsigned u2 = __float_as_uint(v.z), u3 = __float_as_uint(v.w);
    if ((u0 >> 24) == sb1) atomicAdd(&hh[(u0 >> 12) & 0xFFFu], 1u);
    if ((u1 >> 24) == sb1) atomicAdd(&hh[(u1 >> 12) & 0xFFFu], 1u);
    if ((u2 >> 24) == sb1) atomicAdd(&hh[(u2 >> 12) & 0xFFFu], 1u);
    if ((u3 >> 24) == sb1) atomicAdd(&hh[(u3 >> 12) & 0xFFFu], 1u);
  }
  __syncthreads();
  for (int i = tid; i < 4096; i += 256)
    if (hh[i]) atomicAdd(&h12[(b << 12) + i], hh[i]);
  if (tid == 0) { sB2 = 0xFFFu; sA2 = 0u; }  // null-select fallback
  softBarrier(bar + 16, 64);

  // ---- phase 3: level-2 select + accumulate picked values (20-bit prefix) ----
  sel4096(h12 + (b << 12), KTOP - sA1, sm, &sB2, &sA2);
  const unsigned T20 = (sB1 << 12) | sB2;
  const unsigned ne = KTOP - sA1 - sA2;
  float v0 = 0.f, v1 = 0.f, v2 = 0.f;
  for (int it = 0; it < 16; ++it) {
    int li = it * 256 + tid;
    int pix = (y0 << 9) + li;
    unsigned u20 = __float_as_uint(brightS[li]) >> 12;
    bool take = u20 > T20;
    if (u20 == T20) {
      if (aload(&eqTaken[b * 16]) < ne) {
        unsigned old = atomicAdd(&eqTaken[b * 16], 1u);
        take = old < ne;
      }
    }
    if (take) {  // reshape (C,H,W)->(H*W,C): pixel i -> flat 3i,3i+1,3i+2
      v0 += op[3 * pix];
      v1 += op[3 * pix + 1];
      v2 += op[3 * pix + 2];
    }
  }
  for (int off = 32; off > 0; off >>= 1) {
    v0 += __shfl_down(v0, off);
    v1 += __shfl_down(v1, off);
    v2 += __shfl_down(v2, off);
  }
  int w = tid >> 6;
  if ((tid & 63) == 0) { red[w][0] = v0; red[w][1] = v1; red[w][2] = v2; }
  __syncthreads();
  if (tid == 0) {
    atomicAdd(&Asum[b * 3 + 0], red[0][0] + red[1][0] + red[2][0] + red[3][0]);
    atomicAdd(&Asum[b * 3 + 1], red[0][1] + red[1][1] + red[2][1] + red[3][1]);
    atomicAdd(&Asum[b * 3 + 2], red[0][2] + red[1][2] + red[2][2] + red[3][2]);
  }
  __syncthreads();
  if (tid == 0) {
    unsigned tk = __hip_atomic_fetch_add(doneCnt, 1u, __ATOMIC_RELAXED, __HIP_MEMORY_SCOPE_AGENT);
    lastA = (tk == 511);
  }
  __syncthreads();
  if (lastA && tid < 24)
    outA[3 * HWn * 8 + tid] = atomicAdd(&Asum[tid], 0.f) * (1.0f / (float)KTOP);
}

extern "C" void kernel_launch(void* const* d_in, const int* in_sizes, int n_in,
                              void* d_out, int out_size, void* d_ws, size_t ws_size,
                              hipStream_t stream)
{
  const float* x     = (const float*)d_in[0];
  const float* w1    = (const float*)d_in[1];
  const float* b1    = (const float*)d_in[2];
  const float* w2    = (const float*)d_in[3];
  const float* b2    = (const float*)d_in[4];
  const float* cw    = (const float*)d_in[5];
  const float* cb    = (const float*)d_in[6];
  const float* convw = (const float*)d_in[7];
  const float* convb = (const float*)d_in[8];
  float* out = (float*)d_out;
  char* ws = (char*)d_ws;

  float*    Mbuf      = (float*)(ws);                // 8 MB (channel-max of out)
  unsigned* h1        = (unsigned*)(ws + 8388608);   // 8192
  unsigned* h12       = (unsigned*)(ws + 8396800);   // 131072
  float*    Asum      = (float*)(ws + 8658944);      // 96
  unsigned* eqTaken   = (unsigned*)(ws + 8659040);   // 8*16 u32 = 512 B (padded)
  float*    means     = (float*)(ws + 8659552);      // 96
  unsigned* meansDone = (unsigned*)(ws + 8659648);   // 32
  unsigned* accumDone = (unsigned*)(ws + 8659680);   // 32
  unsigned* barCtr    = (unsigned*)(ws + 8659712);   // 8 batches x 3 x 64B = 1536
  short*    w1Ag      = (short*)(ws + 8661248);      // 4096 B (16-aligned)
  short*    w2Ag      = (short*)(ws + 8665344);      // 6144 B used
  float*    colorG    = (float*)(ws + 8683776);      // 96
  int*      kbTab     = (int*)(ws + 8683904);        // 64 lanes x 8 ints = 2048 B

  // zero h1..barCtr
  hipMemsetAsync(ws + 8388608, 0, 8661248 - 8388608, stream);

  k_means<<<768, 256, 0, stream>>>(x, means, meansDone, w1, b1, w2, cw, cb, w1Ag, w2Ag, kbTab, colorG);
  k_fused<<<dim3(32, 64, 8), 256, 0, stream>>>(x, b1, b2, convw, convb, w1Ag, w2Ag, kbTab, colorG, out, Mbuf);
  k_tail<<<512, 256, 0, stream>>>(Mbuf, out, h1, h12, eqTaken, Asum, barCtr, accumDone, out);
}

// Round 11
// 236.889 us; speedup vs baseline: 1.5277x; 1.0319x over previous
//
#include <hip/hip_runtime.h>
#include <hip/hip_bf16.h>

#define Hn 512
#define Wn 512
#define HWn (512 * 512)
#define KTOP 26214

// hb point stride: 70 u16 = 140 B = 35 dwords (odd) -> conv2 ds_read_b128
// lane bank-start (3n+4q) mod 32, <=2-way aliasing. LDS 26,984 B ->
// 6 blocks/CU cap. (R7-verified best structure.)
#define HBS 70
#define HBROW (18 * HBS)   // 1260 u16 per point-row

typedef __attribute__((ext_vector_type(8))) short frag_ab;  // 8 bf16
typedef __attribute__((ext_vector_type(4))) float frag_cd;  // 4 fp32

__device__ __forceinline__ float sigf(float z) { return 1.0f / (1.0f + __expf(-z)); }

__device__ __forceinline__ short f2bf(float f) {  // RNE fp32 -> bf16
  unsigned u = __float_as_uint(f);
  u += 0x7FFFu + ((u >> 16) & 1u);
  return (short)(u >> 16);
}

__device__ __forceinline__ unsigned aload(const unsigned* p) {
  return __hip_atomic_load(p, __ATOMIC_RELAXED, __HIP_MEMORY_SCOPE_AGENT);
}

// ---- kernel 1: per (b,c) sums of x (color) + last-block runs weight-frag prep ----
__global__ __launch_bounds__(256) void k_means(
    const float* __restrict__ x, float* __restrict__ means, unsigned* __restrict__ doneCnt,
    const float* __restrict__ w1, const float* __restrict__ b1, const float* __restrict__ w2,
    const float* __restrict__ cw, const float* __restrict__ cb,
    short* __restrict__ w1A, short* __restrict__ w2A, int* __restrict__ kbTab,
    float* __restrict__ colorG)
{
  const int tid = threadIdx.x;
  __shared__ int lastS;
  int bc = blockIdx.x >> 5;
  int slice = blockIdx.x & 31;
  const float4* p = (const float4*)(x + bc * HWn + slice * 8192);
  float s = 0.f;
  for (int i = tid; i < 2048; i += 256) { float4 v = p[i]; s += v.x + v.y + v.z + v.w; }
  for (int off = 32; off > 0; off >>= 1) s += __shfl_down(s, off);
  if ((tid & 63) == 0) atomicAdd(&means[bc], s);
  __syncthreads();
  if (tid == 0) {
    unsigned tk = __hip_atomic_fetch_add(doneCnt, 1u, __ATOMIC_RELAXED, __HIP_MEMORY_SCOPE_AGENT);
    lastS = (tk == 767);
  }
  __syncthreads();
  if (!lastS) return;

  // ---- prep (runs once, after all means complete) ----
  // conv1 A-frags: M=64 out-ch (4 chunks of 16), K = 27 taps; slots 27..31
  // are ZERO weights (bias enters via MFMA C-operand in k_fused).
  {
    int chunk = tid >> 6, lane = tid & 63;
    int m = lane & 15, q = lane >> 4;
    for (int j = 0; j < 8; ++j) {
      int k = q * 8 + j;
      float v = (k < 27) ? w1[(chunk * 16 + m) * 27 + k] : 0.f;
      w1A[tid * 8 + j] = f2bf(v);
    }
  }
  // conv1 im2col tap byte-offsets per (lane, j) — replaces per-thread div/mod
  // chains in k_fused with two dwordx4 loads. Slots >=27 dup taps 0..4.
  if (tid < 64) {
    int q = tid >> 4;
    for (int j = 0; j < 8; ++j) {
      int k = q * 8 + j;
      int kk = (k < 27) ? k : (k - 27);
      int ic = kk / 9; int r = kk - ic * 9;
      kbTab[tid * 8 + j] = (ic * 240 + (r / 3) * 20 + (r % 3)) * 2;
    }
  }
  // conv2 A-frags, (dy,oc)-packed: M rows m = dy*3+oc (9 used of 16),
  // K-order = dx-major, ch-minor: step i -> dx=i>>1, ch-half=i&1. 6 steps.
  for (int i = tid; i < 384; i += 256) {
    int step = i >> 6, lane = i & 63;
    int m = lane & 15, q = lane >> 4;
    int dx = step >> 1, half = step & 1;
    int dy = m / 3, oc = m - dy * 3;
    for (int j = 0; j < 8; ++j) {
      int ch = half * 32 + q * 8 + j;
      float v = (m < 9) ? w2[oc * 576 + ch * 9 + dy * 3 + dx] : 0.f;
      w2A[i * 8 + j] = f2bf(v);
    }
  }
  if (tid < 24) {
    int b = tid / 3, oc = tid % 3;
    float z = cb[oc];
    for (int j = 0; j < 3; ++j)
      z += (atomicAdd(&means[b * 3 + j], 0.f) * (1.0f / (float)HWn)) * cw[oc * 3 + j];
    colorG[tid] = sigf(z);
  }
}

// ---- kernel 2: fused conv1+relu+conv2+sigmoid+color+1x1conv+x_out via MFMA ----
// R7-verified structure + T1 XCD swizzle: linear block id is remapped
// swz = (lid&7)<<11 | lid>>3 (bijective, 16384%8==0) so that XCD k
// (hw round-robin = lid%8) owns ALL of batch k's tiles in row-major order.
// One batch's x = 3.1 MB < 4 MB per-XCD L2 -> halo/row-band re-reads and
// the out/Mb writes stay XCD-local.
// NOTE (R3/R9 lesson, confirmed twice): any scheme extending per-thread live
// ranges across a tile/batch loop spills to scratch here. Do not revisit.
__global__ __launch_bounds__(256, 6) void k_fused(
    const float* __restrict__ x, const float* __restrict__ b1,
    const float* __restrict__ b2, const float* __restrict__ convw, const float* __restrict__ convb,
    const short* __restrict__ w1Ag, const short* __restrict__ w2Ag,
    const int* __restrict__ kbTab,
    const float* __restrict__ colorG, float* __restrict__ out, float* __restrict__ Mb)
{
  __shared__ __align__(16) unsigned short xs[720];        // [3][12][20] bf16, halo-2
  __shared__ __align__(16) unsigned short hb[180 * HBS];  // h bf16: [pt][ch] stride 70
  __shared__ float bs[64];
  __shared__ float b2s[3], colorS[3], cwS[12], cbS[4];

  const int tid = threadIdx.x;
  const int wid = tid >> 6, lane = tid & 63;
  const int n = lane & 15, q = lane >> 4;

  // T1 XCD swizzle: lid%8 = XCD -> batch; lid/8 = row-major tile within batch
  const int lid = blockIdx.x + (blockIdx.y << 5) + (blockIdx.z << 11);
  const int swz = ((lid & 7) << 11) | (lid >> 3);
  const int txi = swz & 31, tyi = (swz >> 5) & 63;
  const int tx0 = txi * 16, ty0 = tyi * 8;
  const int b = swz >> 11;
  const bool inter = (txi - 1u) < 30u && (tyi - 1u) < 62u;

  // stage x tile as bf16 (4 px/thread, cvt_pk + ds_write_b64):
  // rows ty0-2..ty0+9, cols tx0-2..tx0+17, zero outside image
  if (tid < 180) {
    int c = tid / 60, rem = tid - c * 60;
    int yy = rem / 5, xq = (rem - yy * 5) * 4;
    int gy = ty0 - 2 + yy, gx0 = tx0 - 2 + xq;
    const float* rp = x + (b * 3 + c) * HWn + (gy << 9) + gx0;
    float v0, v1, v2, v3;
    if (inter) {
      v0 = rp[0]; v1 = rp[1]; v2 = rp[2]; v3 = rp[3];
    } else {
      bool rowok = (unsigned)gy < 512u;
      v0 = (rowok && (unsigned)(gx0 + 0) < 512u) ? rp[0] : 0.f;
      v1 = (rowok && (unsigned)(gx0 + 1) < 512u) ? rp[1] : 0.f;
      v2 = (rowok && (unsigned)(gx0 + 2) < 512u) ? rp[2] : 0.f;
      v3 = (rowok && (unsigned)(gx0 + 3) < 512u) ? rp[3] : 0.f;
    }
    __hip_bfloat162 c01 = __float22bfloat162_rn(make_float2(v0, v1));
    __hip_bfloat162 c23 = __float22bfloat162_rn(make_float2(v2, v3));
    uint2 v2w; v2w.x = *(unsigned*)&c01; v2w.y = *(unsigned*)&c23;
    *(uint2*)(xs + c * 240 + yy * 20 + xq) = v2w;
  }
  if (tid < 64) bs[tid] = b1[tid];
  if (tid < 3)  b2s[tid] = b2[tid];
  if (tid < 3)  colorS[tid] = colorG[b * 3 + tid];
  if (tid < 12) cwS[tid] = convw[tid];
  if (tid < 4)  cbS[tid] = convb[tid];

  frag_ab w1f[4];
#pragma unroll
  for (int ck = 0; ck < 4; ++ck) w1f[ck] = *(const frag_ab*)(w1Ag + (ck * 64 + lane) * 8);

  // conv1 tap byte-offsets from global table (L2-hot, 2x dwordx4)
  int kb[8];
  {
    const int4* kp = (const int4*)(kbTab + lane * 8);
    int4 ka = kp[0], kc = kp[1];
    kb[0] = ka.x; kb[1] = ka.y; kb[2] = ka.z; kb[3] = ka.w;
    kb[4] = kc.x; kb[5] = kc.y; kb[6] = kc.z; kb[7] = kc.w;
  }
  __syncthreads();

  // bias for C-init: D row = q*4 + reg
  float biasr[4][4];
#pragma unroll
  for (int ck = 0; ck < 4; ++ck)
#pragma unroll
    for (int r = 0; r < 4; ++r) biasr[ck][r] = bs[ck * 16 + q * 4 + r];

  // ---- conv1: 180 points (12 groups of 16), 4 ch-chunks ----
  if (inter) {
    for (int g = wid; g < 12; g += 4) {
      int pt = g * 16 + n;
      int ptc = (pt < 180) ? pt : 179;   // pad lanes: clamped read AND store
      int pty = (ptc * 3641) >> 16;      // /18 exact
      int ptx = ptc - pty * 18;
      int baseB = (pty * 20 + ptx) * 2;
      frag_ab B;
#pragma unroll
      for (int j = 0; j < 8; ++j)
        B[j] = *(const short*)((const char*)xs + baseB + kb[j]);
#pragma unroll
      for (int ck = 0; ck < 4; ++ck) {
        frag_cd D = {biasr[ck][0], biasr[ck][1], biasr[ck][2], biasr[ck][3]};
        D = __builtin_amdgcn_mfma_f32_16x16x32_bf16(w1f[ck], B, D, 0, 0, 0);
        float2 p01 = make_float2(fmaxf(D[0], 0.f), fmaxf(D[1], 0.f));
        float2 p23 = make_float2(fmaxf(D[2], 0.f), fmaxf(D[3], 0.f));
        __hip_bfloat162 c01 = __float22bfloat162_rn(p01);  // v_cvt_pk_bf16_f32
        __hip_bfloat162 c23 = __float22bfloat162_rn(p23);
        uint2 v2; v2.x = *(unsigned*)&c01; v2.y = *(unsigned*)&c23;
        *(uint2*)(hb + ptc * HBS + ck * 16 + q * 4) = v2;  // pad lanes: same bytes, same addr
      }
    }
  } else {
    for (int g = wid; g < 12; g += 4) {
      int pt = g * 16 + n;
      int ptc = (pt < 180) ? pt : 179;
      int pty = (ptc * 3641) >> 16;
      int ptx = ptc - pty * 18;
      int baseB = (pty * 20 + ptx) * 2;
      int gy = ty0 - 1 + pty, gx = tx0 - 1 + ptx;
      bool valid = (unsigned)gy < 512u && (unsigned)gx < 512u;
      frag_ab B;
#pragma unroll
      for (int j = 0; j < 8; ++j)
        B[j] = *(const short*)((const char*)xs + baseB + kb[j]);
#pragma unroll
      for (int ck = 0; ck < 4; ++ck) {
        frag_cd D = {biasr[ck][0], biasr[ck][1], biasr[ck][2], biasr[ck][3]};
        D = __builtin_amdgcn_mfma_f32_16x16x32_bf16(w1f[ck], B, D, 0, 0, 0);
        float2 p01 = make_float2(fmaxf(D[0], 0.f), fmaxf(D[1], 0.f));
        float2 p23 = make_float2(fmaxf(D[2], 0.f), fmaxf(D[3], 0.f));
        __hip_bfloat162 c01 = __float22bfloat162_rn(p01);
        __hip_bfloat162 c23 = __float22bfloat162_rn(p23);
        unsigned lo = valid ? *(unsigned*)&c01 : 0u;
        unsigned hi = valid ? *(unsigned*)&c23 : 0u;
        uint2 v2; v2.x = lo; v2.y = hi;
        *(uint2*)(hb + ptc * HBS + ck * 16 + q * 4) = v2;
      }
    }
  }

  // conv2 A-frags (6 K-steps), issued before the barrier so loads overlap it
  frag_ab w2f[6];
#pragma unroll
  for (int i = 0; i < 6; ++i) w2f[i] = *(const frag_ab*)(w2Ag + (i * 64 + lane) * 8);
  __syncthreads();

  // ---- conv2: per point-row r (10 rows), 6 K-steps; D -> dstore overlaid on
  // hb row r (only this wave reads row r, reads complete before writes) ----
  for (int r = wid; r < 10; r += 4) {
    frag_cd acc = {0.f, 0.f, 0.f, 0.f};
#pragma unroll
    for (int i = 0; i < 6; ++i) {
      int dx = i >> 1;
      int chb = (i & 1) * 64 + q * 16;  // byte offset within point's 140B ch-row
      frag_ab Bf = *(const frag_ab*)((const char*)hb + (r * 18 + n + dx) * (HBS * 2) + chb);
      acc = __builtin_amdgcn_mfma_f32_16x16x32_bf16(w2f[i], Bf, acc, 0, 0, 0);
    }
    // D rows m = q*4+reg; only m<9 useful. lane (n,q) -> dstore[r][n*10 + m]
    float* dp = (float*)(hb + r * HBROW) + n * 10 + q * 4;
    if (q < 2) {
      *(float2*)dp = make_float2(acc[0], acc[1]);
      *(float2*)(dp + 2) = make_float2(acc[2], acc[3]);
    } else if (q == 2) {
      dp[0] = acc[0];
    }
  }
  __syncthreads();

  // ---- epilogue: 128 threads, one pixel each; also writes channel-max M ----
  if (tid < 128) {
    int y = tid >> 4, xcol = tid & 15;
    float a0 = b2s[0], a1 = b2s[1], a2 = b2s[2];
#pragma unroll
    for (int dy = 0; dy < 3; ++dy) {
      const float* dp = (const float*)(hb + (y + dy) * HBROW) + xcol * 10 + dy * 3;
      a0 += dp[0]; a1 += dp[1]; a2 += dp[2];
    }
    float ih0 = colorS[0] * sigf(a0);
    float ih1 = colorS[1] * sigf(a1);
    float ih2 = colorS[2] * sigf(a2);
    float Kv = cwS[0] * ih0 + cwS[1]  * ih1 + cwS[2]  * ih2 + cbS[0];
    float f1 = cwS[3] * ih0 + cwS[4]  * ih1 + cwS[5]  * ih2 + cbS[1];
    float f2 = cwS[6] * ih0 + cwS[7]  * ih1 + cwS[8]  * ih2 + cbS[2];
    float f3 = cwS[9] * ih0 + cwS[10] * ih1 + cwS[11] * ih2 + cbS[3];
    float xc0 = __bfloat162float(*(const __hip_bfloat16*)&xs[0 * 240 + (y + 2) * 20 + (xcol + 2)]);
    float xc1 = __bfloat162float(*(const __hip_bfloat16*)&xs[1 * 240 + (y + 2) * 20 + (xcol + 2)]);
    float xc2 = __bfloat162float(*(const __hip_bfloat16*)&xs[2 * 240 + (y + 2) * 20 + (xcol + 2)]);
    int oi = ((ty0 + y) << 9) + (tx0 + xcol);
    float o0 = Kv * xc0 - f1 + xc0;
    float o1 = Kv * xc1 - f2 + xc1;
    float o2 = Kv * xc2 - f3 + xc2;
    out[(b * 3 + 0) * HWn + oi] = o0;
    out[(b * 3 + 1) * HWn + oi] = o1;
    out[(b * 3 + 2) * HWn + oi] = o2;
    Mb[b * HWn + oi] = fmaxf(fmaxf(o0, o1), o2);  // v_max3_f32
  }
}

// ---- per-batch soft barrier, NO cache-wide fences ----
__device__ __forceinline__ void softBarrier(unsigned* ctr, unsigned target) {
  __syncthreads();
  if (threadIdx.x == 0) {
    __hip_atomic_fetch_add(ctr, 1u, __ATOMIC_RELAXED, __HIP_MEMORY_SCOPE_AGENT);
    while (__hip_atomic_load(ctr, __ATOMIC_RELAXED, __HIP_MEMORY_SCOPE_AGENT) < target)
      __builtin_amdgcn_s_sleep(2);
  }
  __syncthreads();
}

// ---- selection helpers reading completed global hists via agent-scope loads ----
__device__ void sel256(const unsigned* __restrict__ h, unsigned kneed,
                       unsigned* sm, unsigned* oBin, unsigned* oAbove)
{
  const int t = threadIdx.x;
  sm[t] = aload(&h[t]);
  __syncthreads();
  for (int d = 1; d < 256; d <<= 1) {
    unsigned add = (t + d < 256) ? sm[t + d] : 0u;
    __syncthreads();
    sm[t] += add;
    __syncthreads();
  }
  unsigned mine = sm[t];
  unsigned nxt = (t < 255) ? sm[t + 1] : 0u;
  if (mine >= kneed && nxt < kneed) { *oBin = (unsigned)t; *oAbove = nxt; }
  __syncthreads();
}

__device__ void sel4096(const unsigned* __restrict__ h, unsigned kneed,
                        unsigned* sm, unsigned* oBin, unsigned* oAbove)
{
  const int t = threadIdx.x;
  unsigned loc[16]; unsigned sum = 0;
#pragma unroll
  for (int i = 0; i < 16; ++i) { loc[i] = aload(&h[t * 16 + i]); sum += loc[i]; }
  sm[t] = sum;
  __syncthreads();
  for (int d = 1; d < 256; d <<= 1) {
    unsigned add = (t + d < 256) ? sm[t + d] : 0u;
    __syncthreads();
    sm[t] += add;
    __syncthreads();
  }
  unsigned mine = sm[t];
  unsigned nxt = (t < 255) ? sm[t + 1] : 0u;
  if (mine >= kneed && nxt < kneed) {
    unsigned acc = nxt;
    for (int i = 15; i >= 0; --i) {
      unsigned c = loc[i];
      if (acc + c >= kneed) { *oBin = (unsigned)(t * 16 + i); *oAbove = acc; break; }
      acc += c;
    }
  }
  __syncthreads();
}

// ---- kernel 3 (persistent, 2 soft barriers): M -> bright(LDS) -> h1 -> h12 -> accum ----
// 8-row strips, 512 blocks (64/batch). T1 XCD swizzle: swz = (lid&7)<<6 |
// lid>>3 -> XCD k owns batch k's 64 strips. Mbuf (1 MB) + op gather reads
// hit the same L2 that k_fused (same swizzle) wrote batch k into, and the
// per-batch softBarrier counters become XCD-local.
__global__ __launch_bounds__(256) void k_tail(
    const float* __restrict__ Mbuf, const float* __restrict__ outv,
    unsigned* __restrict__ h1, unsigned* __restrict__ h12,
    unsigned* __restrict__ eqTaken, float* __restrict__ Asum,
    unsigned* __restrict__ barCtr, unsigned* __restrict__ doneCnt, float* __restrict__ outA)
{
  // union region: phase 1a uses xm[10][516] f32 (20640 B); phases 1b..3 use
  // hh[4096] u32 (16384 B) + sm[256] u32 (1024 B). Disjoint live ranges.
  __shared__ __align__(16) char smem[20640];
  __shared__ __align__(16) float brightS[4096];  // 8 rows x 512
  __shared__ unsigned sB1, sA1, sB2, sA2;
  __shared__ float red[4][3];
  __shared__ int lastA;

  float (*xm)[516] = (float (*)[516])smem;
  unsigned* hh = (unsigned*)smem;
  unsigned* sm = (unsigned*)(smem + 16384);

  const int tid = threadIdx.x;
  const int lid = blockIdx.x;
  const int swz = ((lid & 7) << 6) | (lid >> 3);   // bijective, 512 % 8 == 0
  const int b = swz >> 6, strip = swz & 63;
  const int y0 = strip * 8;
  const float* mp = Mbuf + b * HWn;
  const float* op = outv + b * 3 * HWn;
  unsigned* bar = barCtr + b * 48;  // 2 barriers x 64B stride

  // ---- phase 1a: stage M (reflect halo) -> xm, compute bright -> brightS ----
  for (int idx = tid; idx < 1280; idx += 256) {
    int r = idx >> 7, seg = idx & 127;
    int gy = y0 - 1 + r; gy = (gy < 0) ? -gy : (gy > 511 ? 1022 - gy : gy);
    int c0 = seg * 4;
    float4 v = *(const float4*)(mp + (gy << 9) + c0);
    xm[r][c0 + 1] = v.x;
    xm[r][c0 + 2] = v.y;
    xm[r][c0 + 3] = v.z;
    xm[r][c0 + 4] = v.w;
  }
  if (tid < 20) {
    int r = tid >> 1, side = tid & 1;
    int gy = y0 - 1 + r; gy = (gy < 0) ? -gy : (gy > 511 ? 1022 - gy : gy);
    int gx = side ? 510 : 1;  // reflect of col 512 / col -1
    xm[r][side ? 513 : 0] = mp[(gy << 9) + gx];
  }
  __syncthreads();
  {
    const int row = tid >> 5, cl = tid & 31;
#pragma unroll 4
    for (int i = 0; i < 16; ++i) {
      int c = cl + (i << 5);   // consecutive lanes -> consecutive cols
      float s0 = xm[row][c]     + xm[row][c + 1]     + xm[row][c + 2];
      float s1 = xm[row + 1][c] + xm[row + 1][c + 1] + xm[row + 1][c + 2];
      float s2 = xm[row + 2][c] + xm[row + 2][c + 1] + xm[row + 2][c + 2];
      float s = (s0 + s1 + s2) * (1.f / 9.f) + xm[row + 1][c + 1] * (8.f / 9.f);
      s = fmaxf(s, 0.f);
      brightS[(row << 9) + c] = s;
    }
  }
  __syncthreads();  // xm dead from here; hh/sm own the union region

  // ---- phase 1b: 256-bin h1 from brightS (register-cached exponent bins) ----
  hh[tid] = 0;
  __syncthreads();
  {
    unsigned cb0 = 0x100, cc0 = 0, cb1 = 0x100, cc1 = 0;
    const float4* bp4 = (const float4*)brightS;
#pragma unroll
    for (int it = 0; it < 4; ++it) {
      float4 v = bp4[it * 256 + tid];
      unsigned bins[4] = { __float_as_uint(v.x) >> 24, __float_as_uint(v.y) >> 24,
                           __float_as_uint(v.z) >> 24, __float_as_uint(v.w) >> 24 };
#pragma unroll
      for (int j = 0; j < 4; ++j) {
        unsigned bb = bins[j];
        if (bb == cb0) ++cc0;
        else if (bb == cb1) ++cc1;
        else if (!cc0) { cb0 = bb; cc0 = 1; }
        else if (!cc1) { cb1 = bb; cc1 = 1; }
        else atomicAdd(&hh[bb], 1u);
      }
    }
    if (cc0) atomicAdd(&hh[cb0], cc0);
    if (cc1) atomicAdd(&hh[cb1], cc1);
  }
  __syncthreads();
  if (hh[tid]) atomicAdd(&h1[(b << 8) + tid], hh[tid]);
  softBarrier(bar, 64);

  // ---- phase 2: level-1 select + 4096-bin level-2 hist over own pixels ----
  sel256(h1 + (b << 8), KTOP, sm, &sB1, &sA1);
  for (int i = tid; i < 4096; i += 256) hh[i] = 0;
  __syncthreads();
  const float4* bp = (const float4*)brightS;
  const unsigned sb1 = sB1;
#pragma unroll
  for (int it = 0; it < 4; ++it) {
    float4 v = bp[it * 256 + tid];
    unsigned u0 = __float_as_uint(v.x), u1 = __float_as_uint(v.y);
    unsigned u2 = __float_as_uint(v.z), u3 = __float_as_uint(v.w);
    if ((u0 >> 24) == sb1) atomicAdd(&hh[(u0 >> 12) & 0xFFFu], 1u);
    if ((u1 >> 24) == sb1) atomicAdd(&hh[(u1 >> 12) & 0xFFFu], 1u);
    if ((u2 >> 24) == sb1) atomicAdd(&hh[(u2 >> 12) & 0xFFFu], 1u);
    if ((u3 >> 24) == sb1) atomicAdd(&hh[(u3 >> 12) & 0xFFFu], 1u);
  }
  __syncthreads();
  for (int i = tid; i < 4096; i += 256)
    if (hh[i]) atomicAdd(&h12[(b << 12) + i], hh[i]);
  if (tid == 0) { sB2 = 0xFFFu; sA2 = 0u; }  // null-select fallback
  softBarrier(bar + 16, 64);

  // ---- phase 3: level-2 select + accumulate picked values (20-bit prefix) ----
  sel4096(h12 + (b << 12), KTOP - sA1, sm, &sB2, &sA2);
  const unsigned T20 = (sB1 << 12) | sB2;
  const unsigned ne = KTOP - sA1 - sA2;
  float v0 = 0.f, v1 = 0.f, v2 = 0.f;
  for (int it = 0; it < 16; ++it) {
    int li = it * 256 + tid;
    int pix = (y0 << 9) + li;
    unsigned u20 = __float_as_uint(brightS[li]) >> 12;
    bool take = u20 > T20;
    if (u20 == T20) {
      if (aload(&eqTaken[b * 16]) < ne) {
        unsigned old = atomicAdd(&eqTaken[b * 16], 1u);
        take = old < ne;
      }
    }
    if (take) {  // reshape (C,H,W)->(H*W,C): pixel i -> flat 3i,3i+1,3i+2
      v0 += op[3 * pix];
      v1 += op[3 * pix + 1];
      v2 += op[3 * pix + 2];
    }
  }
  for (int off = 32; off > 0; off >>= 1) {
    v0 += __shfl_down(v0, off);
    v1 += __shfl_down(v1, off);
    v2 += __shfl_down(v2, off);
  }
  int w = tid >> 6;
  if ((tid & 63) == 0) { red[w][0] = v0; red[w][1] = v1; red[w][2] = v2; }
  __syncthreads();
  if (tid == 0) {
    atomicAdd(&Asum[b * 3 + 0], red[0][0] + red[1][0] + red[2][0] + red[3][0]);
    atomicAdd(&Asum[b * 3 + 1], red[0][1] + red[1][1] + red[2][1] + red[3][1]);
    atomicAdd(&Asum[b * 3 + 2], red[0][2] + red[1][2] + red[2][2] + red[3][2]);
  }
  __syncthreads();
  if (tid == 0) {
    unsigned tk = __hip_atomic_fetch_add(doneCnt, 1u, __ATOMIC_RELAXED, __HIP_MEMORY_SCOPE_AGENT);
    lastA = (tk == 511);
  }
  __syncthreads();
  if (lastA && tid < 24)
    outA[3 * HWn * 8 + tid] = atomicAdd(&Asum[tid], 0.f) * (1.0f / (float)KTOP);
}

extern "C" void kernel_launch(void* const* d_in, const int* in_sizes, int n_in,
                              void* d_out, int out_size, void* d_ws, size_t ws_size,
                              hipStream_t stream)
{
  const float* x     = (const float*)d_in[0];
  const float* w1    = (const float*)d_in[1];
  const float* b1    = (const float*)d_in[2];
  const float* w2    = (const float*)d_in[3];
  const float* b2    = (const float*)d_in[4];
  const float* cw    = (const float*)d_in[5];
  const float* cb    = (const float*)d_in[6];
  const float* convw = (const float*)d_in[7];
  const float* convb = (const float*)d_in[8];
  float* out = (float*)d_out;
  char* ws = (char*)d_ws;

  float*    Mbuf      = (float*)(ws);                // 8 MB (channel-max of out)
  unsigned* h1        = (unsigned*)(ws + 8388608);   // 8192
  unsigned* h12       = (unsigned*)(ws + 8396800);   // 131072
  float*    Asum      = (float*)(ws + 8658944);      // 96
  unsigned* eqTaken   = (unsigned*)(ws + 8659040);   // 8*16 u32 = 512 B (padded)
  float*    means     = (float*)(ws + 8659552);      // 96
  unsigned* meansDone = (unsigned*)(ws + 8659648);   // 32
  unsigned* accumDone = (unsigned*)(ws + 8659680);   // 32
  unsigned* barCtr    = (unsigned*)(ws + 8659712);   // 8 batches x 3 x 64B = 1536
  short*    w1Ag      = (short*)(ws + 8661248);      // 4096 B (16-aligned)
  short*    w2Ag      = (short*)(ws + 8665344);      // 6144 B used
  float*    colorG    = (float*)(ws + 8683776);      // 96
  int*      kbTab     = (int*)(ws + 8683904);        // 64 lanes x 8 ints = 2048 B

  // zero h1..barCtr
  hipMemsetAsync(ws + 8388608, 0, 8661248 - 8388608, stream);

  k_means<<<768, 256, 0, stream>>>(x, means, meansDone, w1, b1, w2, cw, cb, w1Ag, w2Ag, kbTab, colorG);
  k_fused<<<dim3(32, 64, 8), 256, 0, stream>>>(x, b1, b2, convw, convb, w1Ag, w2Ag, kbTab, colorG, out, Mbuf);
  k_tail<<<512, 256, 0, stream>>>(Mbuf, out, h1, h12, eqTaken, Asum, barCtr, accumDone, out);
}

// Round 12
// 236.575 us; speedup vs baseline: 1.5298x; 1.0013x over previous
//
#include <hip/hip_runtime.h>
#include <hip/hip_bf16.h>

#define Hn 512
#define Wn 512
#define HWn (512 * 512)
#define KTOP 26214

// hb point stride: 70 u16 = 140 B = 35 dwords (odd) -> conv2 ds_read_b128
// lane bank-start (3n+4q) mod 32, <=2-way aliasing. LDS 26,984 B ->
// 6 blocks/CU cap. (R7-verified best structure.)
#define HBS 70
#define HBROW (18 * HBS)   // 1260 u16 per point-row

typedef __attribute__((ext_vector_type(8))) short frag_ab;  // 8 bf16
typedef __attribute__((ext_vector_type(4))) float frag_cd;  // 4 fp32

__device__ __forceinline__ float sigf(float z) { return 1.0f / (1.0f + __expf(-z)); }

__device__ __forceinline__ short f2bf(float f) {  // RNE fp32 -> bf16
  unsigned u = __float_as_uint(f);
  u += 0x7FFFu + ((u >> 16) & 1u);
  return (short)(u >> 16);
}

__device__ __forceinline__ unsigned aload(const unsigned* p) {
  return __hip_atomic_load(p, __ATOMIC_RELAXED, __HIP_MEMORY_SCOPE_AGENT);
}

// ---- kernel 1: per (b,c) sums of x (color) + last-block runs weight-frag prep ----
// T1 alignment: lid%8 = XCD = batch, so XCD k streams batch k's x (3.1 MB
// < 4 MB L2) -> k_fused (same batch->XCD map) finds x in XCD-local L2.
__global__ __launch_bounds__(256) void k_means(
    const float* __restrict__ x, float* __restrict__ means, unsigned* __restrict__ doneCnt,
    const float* __restrict__ w1, const float* __restrict__ b1, const float* __restrict__ w2,
    const float* __restrict__ cw, const float* __restrict__ cb,
    short* __restrict__ w1A, short* __restrict__ w2A, int* __restrict__ kbTab,
    float* __restrict__ colorG)
{
  const int tid = threadIdx.x;
  __shared__ int lastS;
  const int lid = blockIdx.x;          // 768 = 8 batches x 3 ch x 32 slices
  const int b = lid & 7;               // XCD = lid%8 owns batch b
  const int r8 = lid >> 3;             // 0..95
  const int c = r8 >> 5, slice = r8 & 31;
  const int bc = b * 3 + c;
  const float4* p = (const float4*)(x + bc * HWn + slice * 8192);
  float s = 0.f;
  for (int i = tid; i < 2048; i += 256) { float4 v = p[i]; s += v.x + v.y + v.z + v.w; }
  for (int off = 32; off > 0; off >>= 1) s += __shfl_down(s, off);
  if ((tid & 63) == 0) atomicAdd(&means[bc], s);
  __syncthreads();
  if (tid == 0) {
    unsigned tk = __hip_atomic_fetch_add(doneCnt, 1u, __ATOMIC_RELAXED, __HIP_MEMORY_SCOPE_AGENT);
    lastS = (tk == 767);
  }
  __syncthreads();
  if (!lastS) return;

  // ---- prep (runs once, after all means complete) ----
  // conv1 A-frags: M=64 out-ch (4 chunks of 16), K = 27 taps; slots 27..31
  // are ZERO weights (bias enters via MFMA C-operand in k_fused).
  {
    int chunk = tid >> 6, lane = tid & 63;
    int m = lane & 15, q = lane >> 4;
    for (int j = 0; j < 8; ++j) {
      int k = q * 8 + j;
      float v = (k < 27) ? w1[(chunk * 16 + m) * 27 + k] : 0.f;
      w1A[tid * 8 + j] = f2bf(v);
    }
  }
  // conv1 im2col tap byte-offsets per (lane, j) — replaces per-thread div/mod
  // chains in k_fused with two dwordx4 loads. Slots >=27 dup taps 0..4.
  if (tid < 64) {
    int q = tid >> 4;
    for (int j = 0; j < 8; ++j) {
      int k = q * 8 + j;
      int kk = (k < 27) ? k : (k - 27);
      int ic = kk / 9; int r = kk - ic * 9;
      kbTab[tid * 8 + j] = (ic * 240 + (r / 3) * 20 + (r % 3)) * 2;
    }
  }
  // conv2 A-frags, (dy,oc)-packed: M rows m = dy*3+oc (9 used of 16),
  // K-order = dx-major, ch-minor: step i -> dx=i>>1, ch-half=i&1. 6 steps.
  for (int i = tid; i < 384; i += 256) {
    int step = i >> 6, lane = i & 63;
    int m = lane & 15, q = lane >> 4;
    int dx = step >> 1, half = step & 1;
    int dy = m / 3, oc = m - dy * 3;
    for (int j = 0; j < 8; ++j) {
      int ch = half * 32 + q * 8 + j;
      float v = (m < 9) ? w2[oc * 576 + ch * 9 + dy * 3 + dx] : 0.f;
      w2A[i * 8 + j] = f2bf(v);
    }
  }
  if (tid < 24) {
    int bb = tid / 3, oc = tid % 3;
    float z = cb[oc];
    for (int j = 0; j < 3; ++j)
      z += (atomicAdd(&means[bb * 3 + j], 0.f) * (1.0f / (float)HWn)) * cw[oc * 3 + j];
    colorG[tid] = sigf(z);
  }
}

// ---- kernel 2: fused conv1+relu+conv2+sigmoid+color+1x1conv+x_out via MFMA ----
// R7-verified structure + T1 XCD swizzle: swz = (lid&7)<<11 | lid>>3
// (bijective, 16384%8==0) so XCD k owns ALL of batch k's tiles in row-major
// order. Batch x = 3.1 MB < 4 MB per-XCD L2 (primed by k_means, same map).
// NOTE (R3/R9 lesson, confirmed twice): any scheme extending per-thread live
// ranges across a tile/batch loop spills to scratch here. Do not revisit.
__global__ __launch_bounds__(256, 6) void k_fused(
    const float* __restrict__ x, const float* __restrict__ b1,
    const float* __restrict__ b2, const float* __restrict__ convw, const float* __restrict__ convb,
    const short* __restrict__ w1Ag, const short* __restrict__ w2Ag,
    const int* __restrict__ kbTab,
    const float* __restrict__ colorG, float* __restrict__ out, float* __restrict__ Mb)
{
  __shared__ __align__(16) unsigned short xs[720];        // [3][12][20] bf16, halo-2
  __shared__ __align__(16) unsigned short hb[180 * HBS];  // h bf16: [pt][ch] stride 70
  __shared__ float bs[64];
  __shared__ float b2s[3], colorS[3], cwS[12], cbS[4];

  const int tid = threadIdx.x;
  const int wid = tid >> 6, lane = tid & 63;
  const int n = lane & 15, q = lane >> 4;

  // T1 XCD swizzle: lid%8 = XCD -> batch; lid/8 = row-major tile within batch
  const int lid = blockIdx.x + (blockIdx.y << 5) + (blockIdx.z << 11);
  const int swz = ((lid & 7) << 11) | (lid >> 3);
  const int txi = swz & 31, tyi = (swz >> 5) & 63;
  const int tx0 = txi * 16, ty0 = tyi * 8;
  const int b = swz >> 11;
  const bool inter = (txi - 1u) < 30u && (tyi - 1u) < 62u;

  // stage x tile as bf16 (4 px/thread, cvt_pk + ds_write_b64):
  // rows ty0-2..ty0+9, cols tx0-2..tx0+17, zero outside image
  if (tid < 180) {
    int c = tid / 60, rem = tid - c * 60;
    int yy = rem / 5, xq = (rem - yy * 5) * 4;
    int gy = ty0 - 2 + yy, gx0 = tx0 - 2 + xq;
    const float* rp = x + (b * 3 + c) * HWn + (gy << 9) + gx0;
    float v0, v1, v2, v3;
    if (inter) {
      v0 = rp[0]; v1 = rp[1]; v2 = rp[2]; v3 = rp[3];
    } else {
      bool rowok = (unsigned)gy < 512u;
      v0 = (rowok && (unsigned)(gx0 + 0) < 512u) ? rp[0] : 0.f;
      v1 = (rowok && (unsigned)(gx0 + 1) < 512u) ? rp[1] : 0.f;
      v2 = (rowok && (unsigned)(gx0 + 2) < 512u) ? rp[2] : 0.f;
      v3 = (rowok && (unsigned)(gx0 + 3) < 512u) ? rp[3] : 0.f;
    }
    __hip_bfloat162 c01 = __float22bfloat162_rn(make_float2(v0, v1));
    __hip_bfloat162 c23 = __float22bfloat162_rn(make_float2(v2, v3));
    uint2 v2w; v2w.x = *(unsigned*)&c01; v2w.y = *(unsigned*)&c23;
    *(uint2*)(xs + c * 240 + yy * 20 + xq) = v2w;
  }
  if (tid < 64) bs[tid] = b1[tid];
  if (tid < 3)  b2s[tid] = b2[tid];
  if (tid < 3)  colorS[tid] = colorG[b * 3 + tid];
  if (tid < 12) cwS[tid] = convw[tid];
  if (tid < 4)  cbS[tid] = convb[tid];

  frag_ab w1f[4];
#pragma unroll
  for (int ck = 0; ck < 4; ++ck) w1f[ck] = *(const frag_ab*)(w1Ag + (ck * 64 + lane) * 8);

  // conv1 tap byte-offsets from global table (L2-hot, 2x dwordx4)
  int kb[8];
  {
    const int4* kp = (const int4*)(kbTab + lane * 8);
    int4 ka = kp[0], kc = kp[1];
    kb[0] = ka.x; kb[1] = ka.y; kb[2] = ka.z; kb[3] = ka.w;
    kb[4] = kc.x; kb[5] = kc.y; kb[6] = kc.z; kb[7] = kc.w;
  }
  __syncthreads();

  // bias for C-init: D row = q*4 + reg
  float biasr[4][4];
#pragma unroll
  for (int ck = 0; ck < 4; ++ck)
#pragma unroll
    for (int r = 0; r < 4; ++r) biasr[ck][r] = bs[ck * 16 + q * 4 + r];

  // ---- conv1: 180 points (12 groups of 16), 4 ch-chunks ----
  if (inter) {
    for (int g = wid; g < 12; g += 4) {
      int pt = g * 16 + n;
      int ptc = (pt < 180) ? pt : 179;   // pad lanes: clamped read AND store
      int pty = (ptc * 3641) >> 16;      // /18 exact
      int ptx = ptc - pty * 18;
      int baseB = (pty * 20 + ptx) * 2;
      frag_ab B;
#pragma unroll
      for (int j = 0; j < 8; ++j)
        B[j] = *(const short*)((const char*)xs + baseB + kb[j]);
#pragma unroll
      for (int ck = 0; ck < 4; ++ck) {
        frag_cd D = {biasr[ck][0], biasr[ck][1], biasr[ck][2], biasr[ck][3]};
        D = __builtin_amdgcn_mfma_f32_16x16x32_bf16(w1f[ck], B, D, 0, 0, 0);
        float2 p01 = make_float2(fmaxf(D[0], 0.f), fmaxf(D[1], 0.f));
        float2 p23 = make_float2(fmaxf(D[2], 0.f), fmaxf(D[3], 0.f));
        __hip_bfloat162 c01 = __float22bfloat162_rn(p01);  // v_cvt_pk_bf16_f32
        __hip_bfloat162 c23 = __float22bfloat162_rn(p23);
        uint2 v2; v2.x = *(unsigned*)&c01; v2.y = *(unsigned*)&c23;
        *(uint2*)(hb + ptc * HBS + ck * 16 + q * 4) = v2;  // pad lanes: same bytes, same addr
      }
    }
  } else {
    for (int g = wid; g < 12; g += 4) {
      int pt = g * 16 + n;
      int ptc = (pt < 180) ? pt : 179;
      int pty = (ptc * 3641) >> 16;
      int ptx = ptc - pty * 18;
      int baseB = (pty * 20 + ptx) * 2;
      int gy = ty0 - 1 + pty, gx = tx0 - 1 + ptx;
      bool valid = (unsigned)gy < 512u && (unsigned)gx < 512u;
      frag_ab B;
#pragma unroll
      for (int j = 0; j < 8; ++j)
        B[j] = *(const short*)((const char*)xs + baseB + kb[j]);
#pragma unroll
      for (int ck = 0; ck < 4; ++ck) {
        frag_cd D = {biasr[ck][0], biasr[ck][1], biasr[ck][2], biasr[ck][3]};
        D = __builtin_amdgcn_mfma_f32_16x16x32_bf16(w1f[ck], B, D, 0, 0, 0);
        float2 p01 = make_float2(fmaxf(D[0], 0.f), fmaxf(D[1], 0.f));
        float2 p23 = make_float2(fmaxf(D[2], 0.f), fmaxf(D[3], 0.f));
        __hip_bfloat162 c01 = __float22bfloat162_rn(p01);
        __hip_bfloat162 c23 = __float22bfloat162_rn(p23);
        unsigned lo = valid ? *(unsigned*)&c01 : 0u;
        unsigned hi = valid ? *(unsigned*)&c23 : 0u;
        uint2 v2; v2.x = lo; v2.y = hi;
        *(uint2*)(hb + ptc * HBS + ck * 16 + q * 4) = v2;
      }
    }
  }

  // conv2 A-frags (6 K-steps), issued before the barrier so loads overlap it
  frag_ab w2f[6];
#pragma unroll
  for (int i = 0; i < 6; ++i) w2f[i] = *(const frag_ab*)(w2Ag + (i * 64 + lane) * 8);
  __syncthreads();

  // ---- conv2: per point-row r (10 rows), 6 K-steps; D -> dstore overlaid on
  // hb row r (only this wave reads row r, reads complete before writes) ----
  for (int r = wid; r < 10; r += 4) {
    frag_cd acc = {0.f, 0.f, 0.f, 0.f};
#pragma unroll
    for (int i = 0; i < 6; ++i) {
      int dx = i >> 1;
      int chb = (i & 1) * 64 + q * 16;  // byte offset within point's 140B ch-row
      frag_ab Bf = *(const frag_ab*)((const char*)hb + (r * 18 + n + dx) * (HBS * 2) + chb);
      acc = __builtin_amdgcn_mfma_f32_16x16x32_bf16(w2f[i], Bf, acc, 0, 0, 0);
    }
    // D rows m = q*4+reg; only m<9 useful. lane (n,q) -> dstore[r][n*10 + m]
    float* dp = (float*)(hb + r * HBROW) + n * 10 + q * 4;
    if (q < 2) {
      *(float2*)dp = make_float2(acc[0], acc[1]);
      *(float2*)(dp + 2) = make_float2(acc[2], acc[3]);
    } else if (q == 2) {
      dp[0] = acc[0];
    }
  }
  __syncthreads();

  // ---- epilogue: 128 threads, one pixel each; also writes channel-max M ----
  if (tid < 128) {
    int y = tid >> 4, xcol = tid & 15;
    float a0 = b2s[0], a1 = b2s[1], a2 = b2s[2];
#pragma unroll
    for (int dy = 0; dy < 3; ++dy) {
      const float* dp = (const float*)(hb + (y + dy) * HBROW) + xcol * 10 + dy * 3;
      a0 += dp[0]; a1 += dp[1]; a2 += dp[2];
    }
    float ih0 = colorS[0] * sigf(a0);
    float ih1 = colorS[1] * sigf(a1);
    float ih2 = colorS[2] * sigf(a2);
    float Kv = cwS[0] * ih0 + cwS[1]  * ih1 + cwS[2]  * ih2 + cbS[0];
    float f1 = cwS[3] * ih0 + cwS[4]  * ih1 + cwS[5]  * ih2 + cbS[1];
    float f2 = cwS[6] * ih0 + cwS[7]  * ih1 + cwS[8]  * ih2 + cbS[2];
    float f3 = cwS[9] * ih0 + cwS[10] * ih1 + cwS[11] * ih2 + cbS[3];
    float xc0 = __bfloat162float(*(const __hip_bfloat16*)&xs[0 * 240 + (y + 2) * 20 + (xcol + 2)]);
    float xc1 = __bfloat162float(*(const __hip_bfloat16*)&xs[1 * 240 + (y + 2) * 20 + (xcol + 2)]);
    float xc2 = __bfloat162float(*(const __hip_bfloat16*)&xs[2 * 240 + (y + 2) * 20 + (xcol + 2)]);
    int oi = ((ty0 + y) << 9) + (tx0 + xcol);
    float o0 = Kv * xc0 - f1 + xc0;
    float o1 = Kv * xc1 - f2 + xc1;
    float o2 = Kv * xc2 - f3 + xc2;
    out[(b * 3 + 0) * HWn + oi] = o0;
    out[(b * 3 + 1) * HWn + oi] = o1;
    out[(b * 3 + 2) * HWn + oi] = o2;
    Mb[b * HWn + oi] = fmaxf(fmaxf(o0, o1), o2);  // v_max3_f32
  }
}

// ---- per-batch soft barrier, NO cache-wide fences ----
__device__ __forceinline__ void softBarrier(unsigned* ctr, unsigned target) {
  __syncthreads();
  if (threadIdx.x == 0) {
    __hip_atomic_fetch_add(ctr, 1u, __ATOMIC_RELAXED, __HIP_MEMORY_SCOPE_AGENT);
    while (__hip_atomic_load(ctr, __ATOMIC_RELAXED, __HIP_MEMORY_SCOPE_AGENT) < target)
      __builtin_amdgcn_s_sleep(2);
  }
  __syncthreads();
}

// ---- selection helpers reading completed global hists via agent-scope loads ----
__device__ void sel256(const unsigned* __restrict__ h, unsigned kneed,
                       unsigned* sm, unsigned* oBin, unsigned* oAbove)
{
  const int t = threadIdx.x;
  sm[t] = aload(&h[t]);
  __syncthreads();
  for (int d = 1; d < 256; d <<= 1) {
    unsigned add = (t + d < 256) ? sm[t + d] : 0u;
    __syncthreads();
    sm[t] += add;
    __syncthreads();
  }
  unsigned mine = sm[t];
  unsigned nxt = (t < 255) ? sm[t + 1] : 0u;
  if (mine >= kneed && nxt < kneed) { *oBin = (unsigned)t; *oAbove = nxt; }
  __syncthreads();
}

__device__ void sel4096(const unsigned* __restrict__ h, unsigned kneed,
                        unsigned* sm, unsigned* oBin, unsigned* oAbove)
{
  const int t = threadIdx.x;
  unsigned loc[16]; unsigned sum = 0;
#pragma unroll
  for (int i = 0; i < 16; ++i) { loc[i] = aload(&h[t * 16 + i]); sum += loc[i]; }
  sm[t] = sum;
  __syncthreads();
  for (int d = 1; d < 256; d <<= 1) {
    unsigned add = (t + d < 256) ? sm[t + d] : 0u;
    __syncthreads();
    sm[t] += add;
    __syncthreads();
  }
  unsigned mine = sm[t];
  unsigned nxt = (t < 255) ? sm[t + 1] : 0u;
  if (mine >= kneed && nxt < kneed) {
    unsigned acc = nxt;
    for (int i = 15; i >= 0; --i) {
      unsigned c = loc[i];
      if (acc + c >= kneed) { *oBin = (unsigned)(t * 16 + i); *oAbove = acc; break; }
      acc += c;
    }
  }
  __syncthreads();
}

// ---- kernel 3 (persistent, 2 soft barriers): M -> bright(LDS) -> h1 -> h12 -> accum ----
// 8-row strips, 512 blocks (64/batch). T1 XCD swizzle: swz = (lid&7)<<6 |
// lid>>3 -> XCD k owns batch k's 64 strips; Mbuf/op reads hit the L2 that
// k_fused (same map) wrote, and the per-batch barriers are XCD-local.
__global__ __launch_bounds__(256) void k_tail(
    const float* __restrict__ Mbuf, const float* __restrict__ outv,
    unsigned* __restrict__ h1, unsigned* __restrict__ h12,
    unsigned* __restrict__ eqTaken, float* __restrict__ Asum,
    unsigned* __restrict__ barCtr, unsigned* __restrict__ doneCnt, float* __restrict__ outA)
{
  // union region: phase 1a uses xm[10][516] f32 (20640 B); phases 1b..3 use
  // hh[4096] u32 (16384 B) + sm[256] u32 (1024 B). Disjoint live ranges.
  __shared__ __align__(16) char smem[20640];
  __shared__ __align__(16) float brightS[4096];  // 8 rows x 512
  __shared__ unsigned sB1, sA1, sB2, sA2;
  __shared__ float red[4][3];
  __shared__ int lastA;

  float (*xm)[516] = (float (*)[516])smem;
  unsigned* hh = (unsigned*)smem;
  unsigned* sm = (unsigned*)(smem + 16384);

  const int tid = threadIdx.x;
  const int lid = blockIdx.x;
  const int swz = ((lid & 7) << 6) | (lid >> 3);   // bijective, 512 % 8 == 0
  const int b = swz >> 6, strip = swz & 63;
  const int y0 = strip * 8;
  const float* mp = Mbuf + b * HWn;
  const float* op = outv + b * 3 * HWn;
  unsigned* bar = barCtr + b * 48;  // 2 barriers x 64B stride

  // ---- phase 1a: stage M (reflect halo) -> xm, compute bright -> brightS ----
  for (int idx = tid; idx < 1280; idx += 256) {
    int r = idx >> 7, seg = idx & 127;
    int gy = y0 - 1 + r; gy = (gy < 0) ? -gy : (gy > 511 ? 1022 - gy : gy);
    int c0 = seg * 4;
    float4 v = *(const float4*)(mp + (gy << 9) + c0);
    xm[r][c0 + 1] = v.x;
    xm[r][c0 + 2] = v.y;
    xm[r][c0 + 3] = v.z;
    xm[r][c0 + 4] = v.w;
  }
  if (tid < 20) {
    int r = tid >> 1, side = tid & 1;
    int gy = y0 - 1 + r; gy = (gy < 0) ? -gy : (gy > 511 ? 1022 - gy : gy);
    int gx = side ? 510 : 1;  // reflect of col 512 / col -1
    xm[r][side ? 513 : 0] = mp[(gy << 9) + gx];
  }
  __syncthreads();
  {
    const int row = tid >> 5, cl = tid & 31;
#pragma unroll 4
    for (int i = 0; i < 16; ++i) {
      int c = cl + (i << 5);   // consecutive lanes -> consecutive cols
      float s0 = xm[row][c]     + xm[row][c + 1]     + xm[row][c + 2];
      float s1 = xm[row + 1][c] + xm[row + 1][c + 1] + xm[row + 1][c + 2];
      float s2 = xm[row + 2][c] + xm[row + 2][c + 1] + xm[row + 2][c + 2];
      float s = (s0 + s1 + s2) * (1.f / 9.f) + xm[row + 1][c + 1] * (8.f / 9.f);
      s = fmaxf(s, 0.f);
      brightS[(row << 9) + c] = s;
    }
  }
  __syncthreads();  // xm dead from here; hh/sm own the union region

  // ---- phase 1b: 256-bin h1 from brightS (register-cached exponent bins) ----
  hh[tid] = 0;
  __syncthreads();
  {
    unsigned cb0 = 0x100, cc0 = 0, cb1 = 0x100, cc1 = 0;
    const float4* bp4 = (const float4*)brightS;
#pragma unroll
    for (int it = 0; it < 4; ++it) {
      float4 v = bp4[it * 256 + tid];
      unsigned bins[4] = { __float_as_uint(v.x) >> 24, __float_as_uint(v.y) >> 24,
                           __float_as_uint(v.z) >> 24, __float_as_uint(v.w) >> 24 };
#pragma unroll
      for (int j = 0; j < 4; ++j) {
        unsigned bb = bins[j];
        if (bb == cb0) ++cc0;
        else if (bb == cb1) ++cc1;
        else if (!cc0) { cb0 = bb; cc0 = 1; }
        else if (!cc1) { cb1 = bb; cc1 = 1; }
        else atomicAdd(&hh[bb], 1u);
      }
    }
    if (cc0) atomicAdd(&hh[cb0], cc0);
    if (cc1) atomicAdd(&hh[cb1], cc1);
  }
  __syncthreads();
  if (hh[tid]) atomicAdd(&h1[(b << 8) + tid], hh[tid]);
  softBarrier(bar, 64);

  // ---- phase 2: level-1 select + 4096-bin level-2 hist over own pixels ----
  sel256(h1 + (b << 8), KTOP, sm, &sB1, &sA1);
  for (int i = tid; i < 4096; i += 256) hh[i] = 0;
  __syncthreads();
  const float4* bp = (const float4*)brightS;
  const unsigned sb1 = sB1;
#pragma unroll
  for (int it = 0; it < 4; ++it) {
    float4 v = bp[it * 256 + tid];
    unsigned u0 = __float_as_uint(v.x), u1 = __float_as_uint(v.y);
    unsigned u2 = __float_as_uint(v.z), u3 = __float_as_uint(v.w);
    if ((u0 >> 24) == sb1) atomicAdd(&hh[(u0 >> 12) & 0xFFFu], 1u);
    if ((u1 >> 24) == sb1) atomicAdd(&hh[(u1 >> 12) & 0xFFFu], 1u);
    if ((u2 >> 24) == sb1) atomicAdd(&hh[(u2 >> 12) & 0xFFFu], 1u);
    if ((u3 >> 24) == sb1) atomicAdd(&hh[(u3 >> 12) & 0xFFFu], 1u);
  }
  __syncthreads();
  for (int i = tid; i < 4096; i += 256)
    if (hh[i]) atomicAdd(&h12[(b << 12) + i], hh[i]);
  if (tid == 0) { sB2 = 0xFFFu; sA2 = 0u; }  // null-select fallback
  softBarrier(bar + 16, 64);

  // ---- phase 3: level-2 select + accumulate picked values (20-bit prefix) ----
  sel4096(h12 + (b << 12), KTOP - sA1, sm, &sB2, &sA2);
  const unsigned T20 = (sB1 << 12) | sB2;
  const unsigned ne = KTOP - sA1 - sA2;
  float v0 = 0.f, v1 = 0.f, v2 = 0.f;
  for (int it = 0; it < 16; ++it) {
    int li = it * 256 + tid;
    int pix = (y0 << 9) + li;
    unsigned u20 = __float_as_uint(brightS[li]) >> 12;
    bool take = u20 > T20;
    if (u20 == T20) {
      if (aload(&eqTaken[b * 16]) < ne) {
        unsigned old = atomicAdd(&eqTaken[b * 16], 1u);
        take = old < ne;
      }
    }
    if (take) {  // reshape (C,H,W)->(H*W,C): pixel i -> flat 3i,3i+1,3i+2
      v0 += op[3 * pix];
      v1 += op[3 * pix + 1];
      v2 += op[3 * pix + 2];
    }
  }
  for (int off = 32; off > 0; off >>= 1) {
    v0 += __shfl_down(v0, off);
    v1 += __shfl_down(v1, off);
    v2 += __shfl_down(v2, off);
  }
  int w = tid >> 6;
  if ((tid & 63) == 0) { red[w][0] = v0; red[w][1] = v1; red[w][2] = v2; }
  __syncthreads();
  if (tid == 0) {
    atomicAdd(&Asum[b * 3 + 0], red[0][0] + red[1][0] + red[2][0] + red[3][0]);
    atomicAdd(&Asum[b * 3 + 1], red[0][1] + red[1][1] + red[2][1] + red[3][1]);
    atomicAdd(&Asum[b * 3 + 2], red[0][2] + red[1][2] + red[2][2] + red[3][2]);
  }
  __syncthreads();
  if (tid == 0) {
    unsigned tk = __hip_atomic_fetch_add(doneCnt, 1u, __ATOMIC_RELAXED, __HIP_MEMORY_SCOPE_AGENT);
    lastA = (tk == 511);
  }
  __syncthreads();
  if (lastA && tid < 24)
    outA[3 * HWn * 8 + tid] = atomicAdd(&Asum[tid], 0.f) * (1.0f / (float)KTOP);
}

extern "C" void kernel_launch(void* const* d_in, const int* in_sizes, int n_in,
                              void* d_out, int out_size, void* d_ws, size_t ws_size,
                              hipStream_t stream)
{
  const float* x     = (const float*)d_in[0];
  const float* w1    = (const float*)d_in[1];
  const float* b1    = (const float*)d_in[2];
  const float* w2    = (const float*)d_in[3];
  const float* b2    = (const float*)d_in[4];
  const float* cw    = (const float*)d_in[5];
  const float* cb    = (const float*)d_in[6];
  const float* convw = (const float*)d_in[7];
  const float* convb = (const float*)d_in[8];
  float* out = (float*)d_out;
  char* ws = (char*)d_ws;

  float*    Mbuf      = (float*)(ws);                // 8 MB (channel-max of out)
  unsigned* h1        = (unsigned*)(ws + 8388608);   // 8192
  unsigned* h12       = (unsigned*)(ws + 8396800);   // 131072
  float*    Asum      = (float*)(ws + 8658944);      // 96
  unsigned* eqTaken   = (unsigned*)(ws + 8659040);   // 8*16 u32 = 512 B (padded)
  float*    means     = (float*)(ws + 8659552);      // 96
  unsigned* meansDone = (unsigned*)(ws + 8659648);   // 32
  unsigned* accumDone = (unsigned*)(ws + 8659680);   // 32
  unsigned* barCtr    = (unsigned*)(ws + 8659712);   // 8 batches x 3 x 64B = 1536
  short*    w1Ag      = (short*)(ws + 8661248);      // 4096 B (16-aligned)
  short*    w2Ag      = (short*)(ws + 8665344);      // 6144 B used
  float*    colorG    = (float*)(ws + 8683776);      // 96
  int*      kbTab     = (int*)(ws + 8683904);        // 64 lanes x 8 ints = 2048 B

  // zero h1..barCtr
  hipMemsetAsync(ws + 8388608, 0, 8661248 - 8388608, stream);

  k_means<<<768, 256, 0, stream>>>(x, means, meansDone, w1, b1, w2, cw, cb, w1Ag, w2Ag, kbTab, colorG);
  k_fused<<<dim3(32, 64, 8), 256, 0, stream>>>(x, b1, b2, convw, convb, w1Ag, w2Ag, kbTab, colorG, out, Mbuf);
  k_tail<<<512, 256, 0, stream>>>(Mbuf, out, h1, h12, eqTaken, Asum, barCtr, accumDone, out);
}